// Round 9
// baseline (27313.345 us; speedup 1.0000x reference)
//
#include <hip/hip_runtime.h>
#include <hip/hip_bf16.h>

#define BATCH 8
#define SEQ   2048
#define DIM   1024
#define NLAYER 2

typedef float  f32x4 __attribute__((ext_vector_type(4)));
typedef short  s16x8 __attribute__((ext_vector_type(8)));
typedef unsigned short u16x4 __attribute__((ext_vector_type(4)));

// =====================================================================
// bf16x3 split-precision MFMA GEMM (all GEMMs; proven numerics r7/r8)
// =====================================================================
__device__ __forceinline__ unsigned short bf16_rne(float x) {
  const unsigned u = __float_as_uint(x);
  return (unsigned short)((u + 0x7FFFu + ((u >> 16) & 1u)) >> 16);
}
__device__ __forceinline__ void split_bf16(float x, unsigned short& hi, unsigned short& lo) {
  hi = bf16_rne(x);
  const float hf = __uint_as_float((unsigned)hi << 16);
  lo = bf16_rne(x - hf);
}

template<int TRANSB>
__global__ __launch_bounds__(256)
void gemm_bf16x3(const float* __restrict__ A, const float* __restrict__ B,
                 const float* __restrict__ bias, float* __restrict__ C,
                 int M, int N, int K, float alpha,
                 long long strideA, long long strideB, long long strideC)
{
  constexpr int LK = 40;
  __shared__ unsigned short Ah[128 * LK], Al[128 * LK];
  __shared__ unsigned short Bh[128 * LK], Bl[128 * LK];

  const int z = blockIdx.z;
  A += (size_t)z * strideA;
  B += (size_t)z * strideB;
  C += (size_t)z * strideC;

  const int tid  = threadIdx.x;
  const int row0 = blockIdx.x * 128;
  const int col0 = blockIdx.y * 128;
  const int w    = tid >> 6;
  const int lane = tid & 63;
  const int m0   = (w >> 1) * 64;
  const int n0   = (w & 1) * 64;
  const int half = lane >> 4;
  const int mr   = lane & 15;

  f32x4 acc[4][4];
#pragma unroll
  for (int i = 0; i < 4; ++i)
#pragma unroll
    for (int j = 0; j < 4; ++j) acc[i][j] = (f32x4){0.f, 0.f, 0.f, 0.f};

  for (int k0 = 0; k0 < K; k0 += 32) {
    __syncthreads();
    {
      const int r = tid >> 3, c4 = tid & 7;
#pragma unroll
      for (int rep = 0; rep < 4; ++rep) {
        const int row = r + rep * 32;
        const float4 v = *(const float4*)&A[(size_t)(row0 + row) * K + k0 + c4 * 4];
        unsigned short h0,h1,h2,h3,l0,l1,l2,l3;
        split_bf16(v.x, h0, l0); split_bf16(v.y, h1, l1);
        split_bf16(v.z, h2, l2); split_bf16(v.w, h3, l3);
        *(u16x4*)&Ah[row * LK + c4 * 4] = (u16x4){h0, h1, h2, h3};
        *(u16x4*)&Al[row * LK + c4 * 4] = (u16x4){l0, l1, l2, l3};
      }
    }
    if (TRANSB) {
      const int r = tid >> 3, c4 = tid & 7;
#pragma unroll
      for (int rep = 0; rep < 4; ++rep) {
        const int row = r + rep * 32;
        const float4 v = *(const float4*)&B[(size_t)(col0 + row) * K + k0 + c4 * 4];
        unsigned short h0,h1,h2,h3,l0,l1,l2,l3;
        split_bf16(v.x, h0, l0); split_bf16(v.y, h1, l1);
        split_bf16(v.z, h2, l2); split_bf16(v.w, h3, l3);
        *(u16x4*)&Bh[row * LK + c4 * 4] = (u16x4){h0, h1, h2, h3};
        *(u16x4*)&Bl[row * LK + c4 * 4] = (u16x4){l0, l1, l2, l3};
      }
    } else {
      const int kk8 = tid >> 5, n4 = tid & 31;
#pragma unroll
      for (int rep = 0; rep < 4; ++rep) {
        const int kk = kk8 + rep * 8;
        const float4 v = *(const float4*)&B[(size_t)(k0 + kk) * N + col0 + n4 * 4];
        unsigned short h, l;
        split_bf16(v.x, h, l); Bh[(n4*4+0)*LK + kk] = h; Bl[(n4*4+0)*LK + kk] = l;
        split_bf16(v.y, h, l); Bh[(n4*4+1)*LK + kk] = h; Bl[(n4*4+1)*LK + kk] = l;
        split_bf16(v.z, h, l); Bh[(n4*4+2)*LK + kk] = h; Bl[(n4*4+2)*LK + kk] = l;
        split_bf16(v.w, h, l); Bh[(n4*4+3)*LK + kk] = h; Bl[(n4*4+3)*LK + kk] = l;
      }
    }
    __syncthreads();

    s16x8 ah[4], al[4], bh[4], bl[4];
#pragma unroll
    for (int i = 0; i < 4; ++i) {
      ah[i] = *(const s16x8*)&Ah[(m0 + i*16 + mr) * LK + half * 8];
      al[i] = *(const s16x8*)&Al[(m0 + i*16 + mr) * LK + half * 8];
      bh[i] = *(const s16x8*)&Bh[(n0 + i*16 + mr) * LK + half * 8];
      bl[i] = *(const s16x8*)&Bl[(n0 + i*16 + mr) * LK + half * 8];
    }
#pragma unroll
    for (int i = 0; i < 4; ++i)
#pragma unroll
      for (int j = 0; j < 4; ++j) {
        acc[i][j] = __builtin_amdgcn_mfma_f32_16x16x32_bf16(ah[i], bh[j], acc[i][j], 0, 0, 0);
        acc[i][j] = __builtin_amdgcn_mfma_f32_16x16x32_bf16(ah[i], bl[j], acc[i][j], 0, 0, 0);
        acc[i][j] = __builtin_amdgcn_mfma_f32_16x16x32_bf16(al[i], bh[j], acc[i][j], 0, 0, 0);
      }
  }

#pragma unroll
  for (int j = 0; j < 4; ++j) {
    const int col = col0 + n0 + j * 16 + mr;
    const float bb = bias ? bias[col] : 0.f;
#pragma unroll
    for (int i = 0; i < 4; ++i) {
#pragma unroll
      for (int q = 0; q < 4; ++q) {
        const int row = row0 + m0 + i * 16 + half * 4 + q;
        C[(size_t)row * N + col] = fmaf(alpha, acc[i][j][q], bb);
      }
    }
  }
}

// =====================================================================
// tanh without an OCML call (abs err ~1e-7)
// =====================================================================
__device__ __forceinline__ float fast_tanh(float x) {
  const float a = fabsf(x);
  const float e = __expf(2.0f * a);
  const float t = 1.0f - 2.0f / (e + 1.0f);
  return copysignf(t, x);
}

// =====================================================================
// RNN scan v7 — wave-autonomous, weights REALLY in registers.
// Insight from r3-r8: every variant re-streamed the 4MB weight matrix
// per step (L2 / scratch / LDS ~0.5-1us per step). Fix: one WAVE owns
// (batch, 4 dims) end-to-end. Lane l holds k in [16l, 16l+16):
// weights = 4 rows x 4 f32x4 = 64 VGPRs, loaded ONCE via volatile-asm
// global loads (cannot be rematerialized or sunk into the loop).
//  - 512 WGs x 4 waves = 2048 waves; 2 WGs/CU needed, 4/CU capacity
//    -> co-residency guaranteed (no deadlock possible).
//  - Per step: poll own 4KB h slice (fast sc0 / slow sc0-sc1 merge,
//    r8's dual-visibility; blockIdx&7 keeps batch traffic XCD-local),
//    64 FMA, in-wave fold (masks 1,2 then 4..32), lanes<4 dual-store.
//  - ZERO LDS, ZERO barriers, zero per-step weight traffic. Every wave
//    polls-then-produces with no cross-wave dependency (the r2/r3-
//    proven safe spin pattern; r7's spin-during-produce hazard absent).
// =====================================================================
__global__ __launch_bounds__(256, 2)
void rnn_scan(const float* __restrict__ Pre, float* __restrict__ Hout,
              const float* __restrict__ Whh, const float* __restrict__ bhh)
{
  const int b    = blockIdx.x & 7;            // batch -> XCD (likely)
  const int wv   = threadIdx.x >> 6;          // 0..3
  const int lane = threadIdx.x & 63;
  const int g    = (blockIdx.x >> 3) * 4 + wv;  // 0..255 dim-block
  const int d0   = g * 4;
  const int fl   = ((lane & 1) << 1) | ((lane >> 1) & 1);  // bitrev2(lane&3)

  const float* PreB = Pre  + (size_t)b * SEQ * DIM;
  float*       HB   = Hout + (size_t)b * SEQ * DIM;

  // ---- weights: 64 VGPRs, loaded once, non-rematerializable ----
  f32x4 w[4][4];
#pragma unroll
  for (int r = 0; r < 4; ++r)
#pragma unroll
    for (int q = 0; q < 4; ++q) {
      const float* wp = &Whh[(size_t)(d0 + r) * DIM + lane * 16 + q * 4];
      asm volatile("global_load_dwordx4 %0, %1, off\n\t"
                   "s_waitcnt vmcnt(0)"
                   : "=v"(w[r][q]) : "v"(wp));
    }
  const float biasv = bhh[d0 + fl];

  for (int t = 0; t < SEQ; ++t) {
    const float pre = PreB[(size_t)t * DIM + d0 + fl];

    float acc[4] = {0.f, 0.f, 0.f, 0.f};
    if (t > 0) {
      const float* hp = HB + (size_t)(t - 1) * DIM + lane * 16;
      const float* q0 = hp;
      const float* q1 = hp + 4;
      const float* q2 = hp + 8;
      const float* q3 = hp + 12;
      f32x4 m0, m1, m2, m3;
      while (true) {
        f32x4 f0, f1, f2, f3;
        asm volatile(                      // FAST: own-XCD L2 view
          "global_load_dwordx4 %0, %4, off sc0\n\t"
          "global_load_dwordx4 %1, %5, off sc0\n\t"
          "global_load_dwordx4 %2, %6, off sc0\n\t"
          "global_load_dwordx4 %3, %7, off sc0\n\t"
          "s_waitcnt vmcnt(0)"
          : "=&v"(f0), "=&v"(f1), "=&v"(f2), "=&v"(f3)
          : "v"(q0), "v"(q1), "v"(q2), "v"(q3));
        bool gf = true;
#pragma unroll
        for (int j = 0; j < 4; ++j) {
          gf = gf && (__float_as_uint(f0[j]) != 0xFFFFFFFFu)
                  && (__float_as_uint(f1[j]) != 0xFFFFFFFFu)
                  && (__float_as_uint(f2[j]) != 0xFFFFFFFFu)
                  && (__float_as_uint(f3[j]) != 0xFFFFFFFFu);
        }
        if (__all(gf)) { m0 = f0; m1 = f1; m2 = f2; m3 = f3; break; }

        f32x4 s0, s1, s2, s3;
        asm volatile(                      // SLOW: L3 view (always correct)
          "global_load_dwordx4 %0, %4, off sc0 sc1\n\t"
          "global_load_dwordx4 %1, %5, off sc0 sc1\n\t"
          "global_load_dwordx4 %2, %6, off sc0 sc1\n\t"
          "global_load_dwordx4 %3, %7, off sc0 sc1\n\t"
          "s_waitcnt vmcnt(0)"
          : "=&v"(s0), "=&v"(s1), "=&v"(s2), "=&v"(s3)
          : "v"(q0), "v"(q1), "v"(q2), "v"(q3));
        bool gm = true;
#pragma unroll
        for (int j = 0; j < 4; ++j) {
          m0[j] = (__float_as_uint(f0[j]) != 0xFFFFFFFFu) ? f0[j] : s0[j];
          m1[j] = (__float_as_uint(f1[j]) != 0xFFFFFFFFu) ? f1[j] : s1[j];
          m2[j] = (__float_as_uint(f2[j]) != 0xFFFFFFFFu) ? f2[j] : s2[j];
          m3[j] = (__float_as_uint(f3[j]) != 0xFFFFFFFFu) ? f3[j] : s3[j];
          gm = gm && (__float_as_uint(m0[j]) != 0xFFFFFFFFu)
                  && (__float_as_uint(m1[j]) != 0xFFFFFFFFu)
                  && (__float_as_uint(m2[j]) != 0xFFFFFFFFu)
                  && (__float_as_uint(m3[j]) != 0xFFFFFFFFu);
        }
        if (__all(gm)) break;
      }
#pragma unroll
      for (int r = 0; r < 4; ++r) {
        float a = 0.f;
        a = fmaf(w[r][0].x, m0.x, fmaf(w[r][0].y, m0.y,
            fmaf(w[r][0].z, m0.z, fmaf(w[r][0].w, m0.w, a))));
        a = fmaf(w[r][1].x, m1.x, fmaf(w[r][1].y, m1.y,
            fmaf(w[r][1].z, m1.z, fmaf(w[r][1].w, m1.w, a))));
        a = fmaf(w[r][2].x, m2.x, fmaf(w[r][2].y, m2.y,
            fmaf(w[r][2].z, m2.z, fmaf(w[r][2].w, m2.w, a))));
        a = fmaf(w[r][3].x, m3.x, fmaf(w[r][3].y, m3.y,
            fmaf(w[r][3].z, m3.z, fmaf(w[r][3].w, m3.w, a))));
        acc[r] = a;
      }
    }

    // in-wave reduce: fold 4 accs over masks 1,2; finish 4..32.
    // lane l<4 ends holding row bitrev2(l) = fl.
#pragma unroll
    for (int m = 0; m < 2; ++m) {
      const int mask = 1 << m;
      const int nv   = 2 >> m;
      const bool up  = (lane & mask) != 0;
#pragma unroll
      for (int r = 0; r < nv; ++r) {
        const float lo = up ? acc[r + nv] : acc[r];
        const float hi = up ? acc[r] : acc[r + nv];
        acc[r] = lo + __shfl_xor(hi, mask);
      }
    }
#pragma unroll
    for (int off = 4; off < 64; off <<= 1) acc[0] += __shfl_xor(acc[0], off);

    if (lane < 4) {
      const float v = fast_tanh(pre + acc[0] + biasv);
      float* dst = HB + (size_t)t * DIM + d0 + fl;
      asm volatile(
        "global_store_dword %0, %1, off sc0\n\t"        // fast: own-XCD L2
        "global_store_dword %0, %1, off sc0 sc1"        // slow: through to L3
        :: "v"(dst), "v"(v));
    }
  }
}

// =====================================================================
// Masked softmax, in place, one row per block
// =====================================================================
__global__ __launch_bounds__(256)
void softmax_mask(float* __restrict__ S, const unsigned char* __restrict__ mask)
{
  const size_t row = (size_t)blockIdx.y * gridDim.x + blockIdx.x;
  float* p = S + row * SEQ;
  const unsigned char* mrow = mask + row * SEQ;
  __shared__ float buf[SEQ];
  __shared__ float red[4];
  const int tid = threadIdx.x, lane = tid & 63, wv = tid >> 6;

  float mx = -1e30f;
  for (int i = tid; i < SEQ; i += 256) {
    const float v = mrow[i] ? -1e9f : p[i];
    buf[i] = v;
    mx = fmaxf(mx, v);
  }
#pragma unroll
  for (int off = 1; off < 64; off <<= 1) mx = fmaxf(mx, __shfl_xor(mx, off));
  if (lane == 0) red[wv] = mx;
  __syncthreads();
  mx = fmaxf(fmaxf(red[0], red[1]), fmaxf(red[2], red[3]));

  float s = 0.f;
  for (int i = tid; i < SEQ; i += 256) {
    const float e = __expf(buf[i] - mx);
    buf[i] = e;
    s += e;
  }
#pragma unroll
  for (int off = 1; off < 64; off <<= 1) s += __shfl_xor(s, off);
  __syncthreads();
  if (lane == 0) red[wv] = s;
  __syncthreads();
  s = red[0] + red[1] + red[2] + red[3];
  const float inv = 1.f / s;
  for (int i = tid; i < SEQ; i += 256) p[i] = buf[i] * inv;
}

// =====================================================================
extern "C" void kernel_launch(void* const* d_in, const int* in_sizes, int n_in,
                              void* d_out, int out_size, void* d_ws, size_t ws_size,
                              hipStream_t stream)
{
  (void)in_sizes; (void)n_in; (void)out_size;
  const unsigned char* mask = (const unsigned char*)d_in[0];
  const float* reps = (const float*)d_in[1];
  const float* Wih  = (const float*)d_in[2];
  const float* Whh  = (const float*)d_in[3];
  const float* bih  = (const float*)d_in[4];
  const float* bhh  = (const float*)d_in[5];
  const float* Wq   = (const float*)d_in[6];
  const float* bq   = (const float*)d_in[7];
  const float* Wk   = (const float*)d_in[8];
  const float* bk   = (const float*)d_in[9];
  const float* Wv   = (const float*)d_in[10];
  const float* bv   = (const float*)d_in[11];
  const float* Wo   = (const float*)d_in[12];
  const float* bo   = (const float*)d_in[13];
  float* out = (float*)d_out;

  char* ws = (char*)d_ws;
  float* Hb = (float*)(ws);
  float* Qb = (float*)(ws + ((size_t)64  << 20));
  float* Kb = (float*)(ws + ((size_t)128 << 20));
  float* Vb = (float*)(ws + ((size_t)192 << 20));
  float* Sb = (float*)(ws + ((size_t)256 << 20));
  const size_t needFull = ((size_t)256 << 20) + (size_t)BATCH * SEQ * SEQ * 4;
  const bool fullS = ws_size >= needFull;
  const size_t hBytes = (size_t)BATCH * SEQ * DIM * 4;

  const int M1 = BATCH * SEQ;
  const float scale = 0.03125f;
  const dim3 blk(256);
  const long long sSD = (long long)SEQ * DIM;
  const long long sSS = (long long)SEQ * SEQ;

  const float* X = reps;
  for (int l = 0; l < NLAYER; ++l) {
    const size_t wof = (size_t)l * DIM * DIM;
    const size_t bof = (size_t)l * DIM;
    float* Y = (l == NLAYER - 1) ? out : Qb;

    hipMemsetAsync(Hb, 0xFF, hBytes, stream);
    gemm_bf16x3<1><<<dim3(M1/128, DIM/128, 1), blk, 0, stream>>>(
        X, Wih + wof, bih + bof, Kb, M1, DIM, DIM, 1.f, 0, 0, 0);
    rnn_scan<<<dim3(512), dim3(256), 0, stream>>>(Kb, Hb, Whh + wof, bhh + bof);

    gemm_bf16x3<1><<<dim3(M1/128, DIM/128, 1), blk, 0, stream>>>(
        Hb, Wq + wof, bq + bof, Qb, M1, DIM, DIM, 1.f, 0, 0, 0);
    gemm_bf16x3<1><<<dim3(M1/128, DIM/128, 1), blk, 0, stream>>>(
        Hb, Wk + wof, bk + bof, Kb, M1, DIM, DIM, 1.f, 0, 0, 0);
    gemm_bf16x3<1><<<dim3(M1/128, DIM/128, 1), blk, 0, stream>>>(
        Hb, Wv + wof, bv + bof, Vb, M1, DIM, DIM, 1.f, 0, 0, 0);

    if (fullS) {
      gemm_bf16x3<1><<<dim3(SEQ/128, SEQ/128, BATCH), blk, 0, stream>>>(
          Qb, Kb, nullptr, Sb, SEQ, SEQ, DIM, scale, sSD, sSD, sSS);
      softmax_mask<<<dim3(SEQ, BATCH), blk, 0, stream>>>(Sb, mask);
      gemm_bf16x3<0><<<dim3(SEQ/128, DIM/128, BATCH), blk, 0, stream>>>(
          Sb, Vb, nullptr, Hb, SEQ, DIM, SEQ, 1.f, sSS, sSD, sSD);
    } else {
      for (int bb = 0; bb < BATCH; ++bb) {
        gemm_bf16x3<1><<<dim3(SEQ/128, SEQ/128, 1), blk, 0, stream>>>(
            Qb + (size_t)bb * sSD, Kb + (size_t)bb * sSD, nullptr, Sb,
            SEQ, SEQ, DIM, scale, 0, 0, 0);
        softmax_mask<<<dim3(SEQ, 1), blk, 0, stream>>>(Sb, mask + (size_t)bb * sSS);
        gemm_bf16x3<0><<<dim3(SEQ/128, DIM/128, 1), blk, 0, stream>>>(
            Sb, Vb + (size_t)bb * sSD, nullptr, Hb + (size_t)bb * sSD,
            SEQ, DIM, SEQ, 1.f, 0, 0, 0);
      }
    }
    gemm_bf16x3<1><<<dim3(M1/128, DIM/128, 1), blk, 0, stream>>>(
        Hb, Wo + wof, bo + bof, Y, M1, DIM, DIM, 1.f, 0, 0, 0);
    X = Y;
  }
}

// Round 10
// 19693.695 us; speedup vs baseline: 1.3869x; 1.3869x over previous
//
#include <hip/hip_runtime.h>
#include <hip/hip_bf16.h>

#define BATCH 8
#define SEQ   2048
#define DIM   1024
#define NLAYER 2

typedef float  f32x4 __attribute__((ext_vector_type(4)));
typedef short  s16x8 __attribute__((ext_vector_type(8)));
typedef unsigned short u16x4 __attribute__((ext_vector_type(4)));

// =====================================================================
// bf16x3 split-precision MFMA GEMM (all GEMMs; proven numerics r7/r8)
// =====================================================================
__device__ __forceinline__ unsigned short bf16_rne(float x) {
  const unsigned u = __float_as_uint(x);
  return (unsigned short)((u + 0x7FFFu + ((u >> 16) & 1u)) >> 16);
}
__device__ __forceinline__ void split_bf16(float x, unsigned short& hi, unsigned short& lo) {
  hi = bf16_rne(x);
  const float hf = __uint_as_float((unsigned)hi << 16);
  lo = bf16_rne(x - hf);
}

template<int TRANSB>
__global__ __launch_bounds__(256)
void gemm_bf16x3(const float* __restrict__ A, const float* __restrict__ B,
                 const float* __restrict__ bias, float* __restrict__ C,
                 int M, int N, int K, float alpha,
                 long long strideA, long long strideB, long long strideC)
{
  constexpr int LK = 40;
  __shared__ unsigned short Ah[128 * LK], Al[128 * LK];
  __shared__ unsigned short Bh[128 * LK], Bl[128 * LK];

  const int z = blockIdx.z;
  A += (size_t)z * strideA;
  B += (size_t)z * strideB;
  C += (size_t)z * strideC;

  const int tid  = threadIdx.x;
  const int row0 = blockIdx.x * 128;
  const int col0 = blockIdx.y * 128;
  const int w    = tid >> 6;
  const int lane = tid & 63;
  const int m0   = (w >> 1) * 64;
  const int n0   = (w & 1) * 64;
  const int half = lane >> 4;
  const int mr   = lane & 15;

  f32x4 acc[4][4];
#pragma unroll
  for (int i = 0; i < 4; ++i)
#pragma unroll
    for (int j = 0; j < 4; ++j) acc[i][j] = (f32x4){0.f, 0.f, 0.f, 0.f};

  for (int k0 = 0; k0 < K; k0 += 32) {
    __syncthreads();
    {
      const int r = tid >> 3, c4 = tid & 7;
#pragma unroll
      for (int rep = 0; rep < 4; ++rep) {
        const int row = r + rep * 32;
        const float4 v = *(const float4*)&A[(size_t)(row0 + row) * K + k0 + c4 * 4];
        unsigned short h0,h1,h2,h3,l0,l1,l2,l3;
        split_bf16(v.x, h0, l0); split_bf16(v.y, h1, l1);
        split_bf16(v.z, h2, l2); split_bf16(v.w, h3, l3);
        *(u16x4*)&Ah[row * LK + c4 * 4] = (u16x4){h0, h1, h2, h3};
        *(u16x4*)&Al[row * LK + c4 * 4] = (u16x4){l0, l1, l2, l3};
      }
    }
    if (TRANSB) {
      const int r = tid >> 3, c4 = tid & 7;
#pragma unroll
      for (int rep = 0; rep < 4; ++rep) {
        const int row = r + rep * 32;
        const float4 v = *(const float4*)&B[(size_t)(col0 + row) * K + k0 + c4 * 4];
        unsigned short h0,h1,h2,h3,l0,l1,l2,l3;
        split_bf16(v.x, h0, l0); split_bf16(v.y, h1, l1);
        split_bf16(v.z, h2, l2); split_bf16(v.w, h3, l3);
        *(u16x4*)&Bh[row * LK + c4 * 4] = (u16x4){h0, h1, h2, h3};
        *(u16x4*)&Bl[row * LK + c4 * 4] = (u16x4){l0, l1, l2, l3};
      }
    } else {
      const int kk8 = tid >> 5, n4 = tid & 31;
#pragma unroll
      for (int rep = 0; rep < 4; ++rep) {
        const int kk = kk8 + rep * 8;
        const float4 v = *(const float4*)&B[(size_t)(k0 + kk) * N + col0 + n4 * 4];
        unsigned short h, l;
        split_bf16(v.x, h, l); Bh[(n4*4+0)*LK + kk] = h; Bl[(n4*4+0)*LK + kk] = l;
        split_bf16(v.y, h, l); Bh[(n4*4+1)*LK + kk] = h; Bl[(n4*4+1)*LK + kk] = l;
        split_bf16(v.z, h, l); Bh[(n4*4+2)*LK + kk] = h; Bl[(n4*4+2)*LK + kk] = l;
        split_bf16(v.w, h, l); Bh[(n4*4+3)*LK + kk] = h; Bl[(n4*4+3)*LK + kk] = l;
      }
    }
    __syncthreads();

    s16x8 ah[4], al[4], bh[4], bl[4];
#pragma unroll
    for (int i = 0; i < 4; ++i) {
      ah[i] = *(const s16x8*)&Ah[(m0 + i*16 + mr) * LK + half * 8];
      al[i] = *(const s16x8*)&Al[(m0 + i*16 + mr) * LK + half * 8];
      bh[i] = *(const s16x8*)&Bh[(n0 + i*16 + mr) * LK + half * 8];
      bl[i] = *(const s16x8*)&Bl[(n0 + i*16 + mr) * LK + half * 8];
    }
#pragma unroll
    for (int i = 0; i < 4; ++i)
#pragma unroll
      for (int j = 0; j < 4; ++j) {
        acc[i][j] = __builtin_amdgcn_mfma_f32_16x16x32_bf16(ah[i], bh[j], acc[i][j], 0, 0, 0);
        acc[i][j] = __builtin_amdgcn_mfma_f32_16x16x32_bf16(ah[i], bl[j], acc[i][j], 0, 0, 0);
        acc[i][j] = __builtin_amdgcn_mfma_f32_16x16x32_bf16(al[i], bh[j], acc[i][j], 0, 0, 0);
      }
  }

#pragma unroll
  for (int j = 0; j < 4; ++j) {
    const int col = col0 + n0 + j * 16 + mr;
    const float bb = bias ? bias[col] : 0.f;
#pragma unroll
    for (int i = 0; i < 4; ++i) {
#pragma unroll
      for (int q = 0; q < 4; ++q) {
        const int row = row0 + m0 + i * 16 + half * 4 + q;
        C[(size_t)row * N + col] = fmaf(alpha, acc[i][j][q], bb);
      }
    }
  }
}

// =====================================================================
// tanh without an OCML call (abs err ~1e-7)
// =====================================================================
__device__ __forceinline__ float fast_tanh(float x) {
  const float a = fabsf(x);
  const float e = __expf(2.0f * a);
  const float t = 1.0f - 2.0f / (e + 1.0f);
  return copysignf(t, x);
}

// =====================================================================
// RNN scan v8 = r8's v6 with the serial chain shortened (numerics
// bit-identical; canary absmax 0.0009765625):
//  1. Weight fragments prefetched from LDS into regs BEFORE the
//     barrier: waves 1-7 overlap their 16 ds_read_b128 with wave0's
//     poll (intra-iteration live range -> allocator won't spill;
//     loop-carried residency is impossible per r3/r4/r5/r9 evidence).
//  2. Barrier B + wave0 gather DELETED: each wave's fold already
//     yields complete dot products; lanes<4 of every wave tanh+store
//     their own 4 dims directly (dual-visibility sc0 / sc0+sc1).
//  3. ONE barrier per step; hbuf double-buffered (a wave's reads of
//     buf[t&1] precede its arrival at barrier t+1, which precedes
//     wave0's rewrite at t+2 -> race-free).
// Deadlock-free: 256 WGs x 1/CU co-resident; only wave0 spins.
// =====================================================================
__global__ __launch_bounds__(512, 1)
void rnn_scan(const float* __restrict__ Pre, float* __restrict__ Hout,
              const float* __restrict__ Whh, const float* __restrict__ bhh)
{
  __shared__ float wS[32][DIM];                 // 128 KB
  __shared__ __align__(16) float hbuf[2][DIM];  // 8 KB
  const int b    = blockIdx.x & 7;
  const int p    = blockIdx.x >> 3;      // 0..31
  const int wv   = threadIdx.x >> 6;     // 0..7
  const int lane = threadIdx.x & 63;
  const int fl   = ((lane & 1) << 1) | ((lane >> 1) & 1);  // bitrev2
  const int d0   = p * 32 + wv * 4;

  const float* PreB = Pre  + (size_t)b * SEQ * DIM;
  float*       HB   = Hout + (size_t)b * SEQ * DIM;

  // stage this WG's 32 weight rows into LDS (coalesced float4)
  for (int i = threadIdx.x; i < 32 * (DIM / 4); i += 512) {
    const int row = i >> 8, c4 = i & 255;
    *(f32x4*)&wS[row][c4 * 4] =
        *(const f32x4*)&Whh[(size_t)(p * 32 + row) * DIM + c4 * 4];
  }
  __syncthreads();

  const bool plane  = (lane < 4);
  const float biasv = plane ? bhh[d0 + fl] : 0.f;

  for (int t = 0; t < SEQ; ++t) {
    // --- pre-barrier phase: h-independent work overlaps wave0's poll ---
    f32x4 wr[4][4];
#pragma unroll
    for (int r = 0; r < 4; ++r) {
      wr[r][0] = *(const f32x4*)&wS[wv * 4 + r][  0 + lane * 4];
      wr[r][1] = *(const f32x4*)&wS[wv * 4 + r][256 + lane * 4];
      wr[r][2] = *(const f32x4*)&wS[wv * 4 + r][512 + lane * 4];
      wr[r][3] = *(const f32x4*)&wS[wv * 4 + r][768 + lane * 4];
    }
    float pre = 0.f;
    if (plane) pre = PreB[(size_t)t * DIM + d0 + fl];

    float r0 = 0.f;
    if (t > 0) {
      if (wv == 0) {
        const float* hp = HB + (size_t)(t - 1) * DIM;
        const float* q0 = hp +   0 + lane * 4;
        const float* q1 = hp + 256 + lane * 4;
        const float* q2 = hp + 512 + lane * 4;
        const float* q3 = hp + 768 + lane * 4;
        f32x4 m0, m1, m2, m3;
        while (true) {
          f32x4 f0, f1, f2, f3;
          asm volatile(                      // FAST: own-XCD L2 view
            "global_load_dwordx4 %0, %4, off sc0\n\t"
            "global_load_dwordx4 %1, %5, off sc0\n\t"
            "global_load_dwordx4 %2, %6, off sc0\n\t"
            "global_load_dwordx4 %3, %7, off sc0\n\t"
            "s_waitcnt vmcnt(0)"
            : "=&v"(f0), "=&v"(f1), "=&v"(f2), "=&v"(f3)
            : "v"(q0), "v"(q1), "v"(q2), "v"(q3));
          bool gf = true;
#pragma unroll
          for (int j = 0; j < 4; ++j) {
            gf = gf && (__float_as_uint(f0[j]) != 0xFFFFFFFFu)
                    && (__float_as_uint(f1[j]) != 0xFFFFFFFFu)
                    && (__float_as_uint(f2[j]) != 0xFFFFFFFFu)
                    && (__float_as_uint(f3[j]) != 0xFFFFFFFFu);
          }
          if (__all(gf)) { m0 = f0; m1 = f1; m2 = f2; m3 = f3; break; }

          f32x4 s0, s1, s2, s3;
          asm volatile(                      // SLOW: L3 view (always correct)
            "global_load_dwordx4 %0, %4, off sc0 sc1\n\t"
            "global_load_dwordx4 %1, %5, off sc0 sc1\n\t"
            "global_load_dwordx4 %2, %6, off sc0 sc1\n\t"
            "global_load_dwordx4 %3, %7, off sc0 sc1\n\t"
            "s_waitcnt vmcnt(0)"
            : "=&v"(s0), "=&v"(s1), "=&v"(s2), "=&v"(s3)
            : "v"(q0), "v"(q1), "v"(q2), "v"(q3));
          bool gm = true;
#pragma unroll
          for (int j = 0; j < 4; ++j) {
            m0[j] = (__float_as_uint(f0[j]) != 0xFFFFFFFFu) ? f0[j] : s0[j];
            m1[j] = (__float_as_uint(f1[j]) != 0xFFFFFFFFu) ? f1[j] : s1[j];
            m2[j] = (__float_as_uint(f2[j]) != 0xFFFFFFFFu) ? f2[j] : s2[j];
            m3[j] = (__float_as_uint(f3[j]) != 0xFFFFFFFFu) ? f3[j] : s3[j];
            gm = gm && (__float_as_uint(m0[j]) != 0xFFFFFFFFu)
                    && (__float_as_uint(m1[j]) != 0xFFFFFFFFu)
                    && (__float_as_uint(m2[j]) != 0xFFFFFFFFu)
                    && (__float_as_uint(m3[j]) != 0xFFFFFFFFu);
          }
          if (__all(gm)) break;
        }
        *(f32x4*)&hbuf[t & 1][  0 + lane * 4] = m0;
        *(f32x4*)&hbuf[t & 1][256 + lane * 4] = m1;
        *(f32x4*)&hbuf[t & 1][512 + lane * 4] = m2;
        *(f32x4*)&hbuf[t & 1][768 + lane * 4] = m3;
      }
      __syncthreads();   // the ONLY barrier per step
      const f32x4 h0 = *(const f32x4*)&hbuf[t & 1][  0 + lane * 4];
      const f32x4 h1 = *(const f32x4*)&hbuf[t & 1][256 + lane * 4];
      const f32x4 h2 = *(const f32x4*)&hbuf[t & 1][512 + lane * 4];
      const f32x4 h3 = *(const f32x4*)&hbuf[t & 1][768 + lane * 4];
      float acc[4];
#pragma unroll
      for (int r = 0; r < 4; ++r) {
        float a = 0.f;
        a = fmaf(wr[r][0].x, h0.x, fmaf(wr[r][0].y, h0.y,
            fmaf(wr[r][0].z, h0.z, fmaf(wr[r][0].w, h0.w, a))));
        a = fmaf(wr[r][1].x, h1.x, fmaf(wr[r][1].y, h1.y,
            fmaf(wr[r][1].z, h1.z, fmaf(wr[r][1].w, h1.w, a))));
        a = fmaf(wr[r][2].x, h2.x, fmaf(wr[r][2].y, h2.y,
            fmaf(wr[r][2].z, h2.z, fmaf(wr[r][2].w, h2.w, a))));
        a = fmaf(wr[r][3].x, h3.x, fmaf(wr[r][3].y, h3.y,
            fmaf(wr[r][3].z, h3.z, fmaf(wr[r][3].w, h3.w, a))));
        acc[r] = a;
      }
      // fold 4 accs over masks 1,2; finish 4..32 (same tree as r8)
#pragma unroll
      for (int m = 0; m < 2; ++m) {
        const int mask = 1 << m;
        const int nv   = 2 >> m;
        const bool up  = (lane & mask) != 0;
#pragma unroll
        for (int r = 0; r < nv; ++r) {
          const float lo = up ? acc[r + nv] : acc[r];
          const float hi = up ? acc[r] : acc[r + nv];
          acc[r] = lo + __shfl_xor(hi, mask);
        }
      }
#pragma unroll
      for (int off = 4; off < 64; off <<= 1) acc[0] += __shfl_xor(acc[0], off);
      r0 = acc[0];
    }

    if (plane) {
      const float v = (t > 0) ? fast_tanh(pre + r0 + biasv)
                              : fast_tanh(pre + biasv);
      float* dst = HB + (size_t)t * DIM + d0 + fl;
      asm volatile(
        "global_store_dword %0, %1, off sc0\n\t"        // fast: own-XCD L2
        "global_store_dword %0, %1, off sc0 sc1"        // slow: through to L3
        :: "v"(dst), "v"(v));
    }
  }
}

// =====================================================================
// Masked softmax, in place, one row per block
// =====================================================================
__global__ __launch_bounds__(256)
void softmax_mask(float* __restrict__ S, const unsigned char* __restrict__ mask)
{
  const size_t row = (size_t)blockIdx.y * gridDim.x + blockIdx.x;
  float* p = S + row * SEQ;
  const unsigned char* mrow = mask + row * SEQ;
  __shared__ float buf[SEQ];
  __shared__ float red[4];
  const int tid = threadIdx.x, lane = tid & 63, wv = tid >> 6;

  float mx = -1e30f;
  for (int i = tid; i < SEQ; i += 256) {
    const float v = mrow[i] ? -1e9f : p[i];
    buf[i] = v;
    mx = fmaxf(mx, v);
  }
#pragma unroll
  for (int off = 1; off < 64; off <<= 1) mx = fmaxf(mx, __shfl_xor(mx, off));
  if (lane == 0) red[wv] = mx;
  __syncthreads();
  mx = fmaxf(fmaxf(red[0], red[1]), fmaxf(red[2], red[3]));

  float s = 0.f;
  for (int i = tid; i < SEQ; i += 256) {
    const float e = __expf(buf[i] - mx);
    buf[i] = e;
    s += e;
  }
#pragma unroll
  for (int off = 1; off < 64; off <<= 1) s += __shfl_xor(s, off);
  __syncthreads();
  if (lane == 0) red[wv] = s;
  __syncthreads();
  s = red[0] + red[1] + red[2] + red[3];
  const float inv = 1.f / s;
  for (int i = tid; i < SEQ; i += 256) p[i] = buf[i] * inv;
}

// =====================================================================
extern "C" void kernel_launch(void* const* d_in, const int* in_sizes, int n_in,
                              void* d_out, int out_size, void* d_ws, size_t ws_size,
                              hipStream_t stream)
{
  (void)in_sizes; (void)n_in; (void)out_size;
  const unsigned char* mask = (const unsigned char*)d_in[0];
  const float* reps = (const float*)d_in[1];
  const float* Wih  = (const float*)d_in[2];
  const float* Whh  = (const float*)d_in[3];
  const float* bih  = (const float*)d_in[4];
  const float* bhh  = (const float*)d_in[5];
  const float* Wq   = (const float*)d_in[6];
  const float* bq   = (const float*)d_in[7];
  const float* Wk   = (const float*)d_in[8];
  const float* bk   = (const float*)d_in[9];
  const float* Wv   = (const float*)d_in[10];
  const float* bv   = (const float*)d_in[11];
  const float* Wo   = (const float*)d_in[12];
  const float* bo   = (const float*)d_in[13];
  float* out = (float*)d_out;

  char* ws = (char*)d_ws;
  float* Hb = (float*)(ws);
  float* Qb = (float*)(ws + ((size_t)64  << 20));
  float* Kb = (float*)(ws + ((size_t)128 << 20));
  float* Vb = (float*)(ws + ((size_t)192 << 20));
  float* Sb = (float*)(ws + ((size_t)256 << 20));
  const size_t needFull = ((size_t)256 << 20) + (size_t)BATCH * SEQ * SEQ * 4;
  const bool fullS = ws_size >= needFull;
  const size_t hBytes = (size_t)BATCH * SEQ * DIM * 4;

  const int M1 = BATCH * SEQ;
  const float scale = 0.03125f;
  const dim3 blk(256);
  const long long sSD = (long long)SEQ * DIM;
  const long long sSS = (long long)SEQ * SEQ;

  const float* X = reps;
  for (int l = 0; l < NLAYER; ++l) {
    const size_t wof = (size_t)l * DIM * DIM;
    const size_t bof = (size_t)l * DIM;
    float* Y = (l == NLAYER - 1) ? out : Qb;

    hipMemsetAsync(Hb, 0xFF, hBytes, stream);
    gemm_bf16x3<1><<<dim3(M1/128, DIM/128, 1), blk, 0, stream>>>(
        X, Wih + wof, bih + bof, Kb, M1, DIM, DIM, 1.f, 0, 0, 0);
    rnn_scan<<<dim3(256), dim3(512), 0, stream>>>(Kb, Hb, Whh + wof, bhh + bof);

    gemm_bf16x3<1><<<dim3(M1/128, DIM/128, 1), blk, 0, stream>>>(
        Hb, Wq + wof, bq + bof, Qb, M1, DIM, DIM, 1.f, 0, 0, 0);
    gemm_bf16x3<1><<<dim3(M1/128, DIM/128, 1), blk, 0, stream>>>(
        Hb, Wk + wof, bk + bof, Kb, M1, DIM, DIM, 1.f, 0, 0, 0);
    gemm_bf16x3<1><<<dim3(M1/128, DIM/128, 1), blk, 0, stream>>>(
        Hb, Wv + wof, bv + bof, Vb, M1, DIM, DIM, 1.f, 0, 0, 0);

    if (fullS) {
      gemm_bf16x3<1><<<dim3(SEQ/128, SEQ/128, BATCH), blk, 0, stream>>>(
          Qb, Kb, nullptr, Sb, SEQ, SEQ, DIM, scale, sSD, sSD, sSS);
      softmax_mask<<<dim3(SEQ, BATCH), blk, 0, stream>>>(Sb, mask);
      gemm_bf16x3<0><<<dim3(SEQ/128, DIM/128, BATCH), blk, 0, stream>>>(
          Sb, Vb, nullptr, Hb, SEQ, DIM, SEQ, 1.f, sSS, sSD, sSD);
    } else {
      for (int bb = 0; bb < BATCH; ++bb) {
        gemm_bf16x3<1><<<dim3(SEQ/128, SEQ/128, 1), blk, 0, stream>>>(
            Qb + (size_t)bb * sSD, Kb + (size_t)bb * sSD, nullptr, Sb,
            SEQ, SEQ, DIM, scale, 0, 0, 0);
        softmax_mask<<<dim3(SEQ, 1), blk, 0, stream>>>(Sb, mask + (size_t)bb * sSS);
        gemm_bf16x3<0><<<dim3(SEQ/128, DIM/128, 1), blk, 0, stream>>>(
            Sb, Vb + (size_t)bb * sSD, nullptr, Hb + (size_t)bb * sSD,
            SEQ, DIM, SEQ, 1.f, 0, 0, 0);
      }
    }
    gemm_bf16x3<1><<<dim3(M1/128, DIM/128, 1), blk, 0, stream>>>(
        Hb, Wo + wof, bo + bof, Y, M1, DIM, DIM, 1.f, 0, 0, 0);
    X = Y;
  }
}

// Round 11
// 11359.401 us; speedup vs baseline: 2.4045x; 1.7337x over previous
//
#include <hip/hip_runtime.h>
#include <hip/hip_bf16.h>

#define BATCH 8
#define SEQ   2048
#define DIM   1024
#define NLAYER 2

typedef float  f32x4 __attribute__((ext_vector_type(4)));
typedef short  s16x8 __attribute__((ext_vector_type(8)));
typedef unsigned short u16x4 __attribute__((ext_vector_type(4)));

// =====================================================================
// bf16x3 split-precision MFMA GEMM (all GEMMs; proven numerics r7-r10)
// =====================================================================
__device__ __forceinline__ unsigned short bf16_rne(float x) {
  const unsigned u = __float_as_uint(x);
  return (unsigned short)((u + 0x7FFFu + ((u >> 16) & 1u)) >> 16);
}
__device__ __forceinline__ void split_bf16(float x, unsigned short& hi, unsigned short& lo) {
  hi = bf16_rne(x);
  const float hf = __uint_as_float((unsigned)hi << 16);
  lo = bf16_rne(x - hf);
}

template<int TRANSB>
__global__ __launch_bounds__(256)
void gemm_bf16x3(const float* __restrict__ A, const float* __restrict__ B,
                 const float* __restrict__ bias, float* __restrict__ C,
                 int M, int N, int K, float alpha,
                 long long strideA, long long strideB, long long strideC)
{
  constexpr int LK = 40;
  __shared__ unsigned short Ah[128 * LK], Al[128 * LK];
  __shared__ unsigned short Bh[128 * LK], Bl[128 * LK];

  const int z = blockIdx.z;
  A += (size_t)z * strideA;
  B += (size_t)z * strideB;
  C += (size_t)z * strideC;

  const int tid  = threadIdx.x;
  const int row0 = blockIdx.x * 128;
  const int col0 = blockIdx.y * 128;
  const int w    = tid >> 6;
  const int lane = tid & 63;
  const int m0   = (w >> 1) * 64;
  const int n0   = (w & 1) * 64;
  const int half = lane >> 4;
  const int mr   = lane & 15;

  f32x4 acc[4][4];
#pragma unroll
  for (int i = 0; i < 4; ++i)
#pragma unroll
    for (int j = 0; j < 4; ++j) acc[i][j] = (f32x4){0.f, 0.f, 0.f, 0.f};

  for (int k0 = 0; k0 < K; k0 += 32) {
    __syncthreads();
    {
      const int r = tid >> 3, c4 = tid & 7;
#pragma unroll
      for (int rep = 0; rep < 4; ++rep) {
        const int row = r + rep * 32;
        const float4 v = *(const float4*)&A[(size_t)(row0 + row) * K + k0 + c4 * 4];
        unsigned short h0,h1,h2,h3,l0,l1,l2,l3;
        split_bf16(v.x, h0, l0); split_bf16(v.y, h1, l1);
        split_bf16(v.z, h2, l2); split_bf16(v.w, h3, l3);
        *(u16x4*)&Ah[row * LK + c4 * 4] = (u16x4){h0, h1, h2, h3};
        *(u16x4*)&Al[row * LK + c4 * 4] = (u16x4){l0, l1, l2, l3};
      }
    }
    if (TRANSB) {
      const int r = tid >> 3, c4 = tid & 7;
#pragma unroll
      for (int rep = 0; rep < 4; ++rep) {
        const int row = r + rep * 32;
        const float4 v = *(const float4*)&B[(size_t)(col0 + row) * K + k0 + c4 * 4];
        unsigned short h0,h1,h2,h3,l0,l1,l2,l3;
        split_bf16(v.x, h0, l0); split_bf16(v.y, h1, l1);
        split_bf16(v.z, h2, l2); split_bf16(v.w, h3, l3);
        *(u16x4*)&Bh[row * LK + c4 * 4] = (u16x4){h0, h1, h2, h3};
        *(u16x4*)&Bl[row * LK + c4 * 4] = (u16x4){l0, l1, l2, l3};
      }
    } else {
      const int kk8 = tid >> 5, n4 = tid & 31;
#pragma unroll
      for (int rep = 0; rep < 4; ++rep) {
        const int kk = kk8 + rep * 8;
        const float4 v = *(const float4*)&B[(size_t)(k0 + kk) * N + col0 + n4 * 4];
        unsigned short h, l;
        split_bf16(v.x, h, l); Bh[(n4*4+0)*LK + kk] = h; Bl[(n4*4+0)*LK + kk] = l;
        split_bf16(v.y, h, l); Bh[(n4*4+1)*LK + kk] = h; Bl[(n4*4+1)*LK + kk] = l;
        split_bf16(v.z, h, l); Bh[(n4*4+2)*LK + kk] = h; Bl[(n4*4+2)*LK + kk] = l;
        split_bf16(v.w, h, l); Bh[(n4*4+3)*LK + kk] = h; Bl[(n4*4+3)*LK + kk] = l;
      }
    }
    __syncthreads();

    s16x8 ah[4], al[4], bh[4], bl[4];
#pragma unroll
    for (int i = 0; i < 4; ++i) {
      ah[i] = *(const s16x8*)&Ah[(m0 + i*16 + mr) * LK + half * 8];
      al[i] = *(const s16x8*)&Al[(m0 + i*16 + mr) * LK + half * 8];
      bh[i] = *(const s16x8*)&Bh[(n0 + i*16 + mr) * LK + half * 8];
      bl[i] = *(const s16x8*)&Bl[(n0 + i*16 + mr) * LK + half * 8];
    }
#pragma unroll
    for (int i = 0; i < 4; ++i)
#pragma unroll
      for (int j = 0; j < 4; ++j) {
        acc[i][j] = __builtin_amdgcn_mfma_f32_16x16x32_bf16(ah[i], bh[j], acc[i][j], 0, 0, 0);
        acc[i][j] = __builtin_amdgcn_mfma_f32_16x16x32_bf16(ah[i], bl[j], acc[i][j], 0, 0, 0);
        acc[i][j] = __builtin_amdgcn_mfma_f32_16x16x32_bf16(al[i], bh[j], acc[i][j], 0, 0, 0);
      }
  }

#pragma unroll
  for (int j = 0; j < 4; ++j) {
    const int col = col0 + n0 + j * 16 + mr;
    const float bb = bias ? bias[col] : 0.f;
#pragma unroll
    for (int i = 0; i < 4; ++i) {
#pragma unroll
      for (int q = 0; q < 4; ++q) {
        const int row = row0 + m0 + i * 16 + half * 4 + q;
        C[(size_t)row * N + col] = fmaf(alpha, acc[i][j][q], bb);
      }
    }
  }
}

// =====================================================================
// tanh without an OCML call (abs err ~1e-7)
// =====================================================================
__device__ __forceinline__ float fast_tanh(float x) {
  const float a = fabsf(x);
  const float e = __expf(2.0f * a);
  const float t = 1.0f - 2.0f / (e + 1.0f);
  return copysignf(t, x);
}

// =====================================================================
// RNN scan v9 = r8's proven v6 structure (wave0 poll + LDS broadcast,
// two barriers, wave0 gather + ONE coalesced dual-visibility store —
// r10 proved per-wave scatter stores regress 70%), with the serial
// chain shortened by hoisting h-INDEPENDENT work ahead of the barrier:
//  1. Weight fragments LDS->regs prefetched: waves 1-7 before the poll
//     (overlaps wave0's spin), wave0 after its hbuf write (completes
//     under the barrier wait). r8 paid ~0.3-0.45us of post-barrier
//     ds_read serialization per step; now hidden.
//  2. pre (input GEMM value) loaded at iteration top instead of after
//     barrier B (was an L2-latency tail on the chain).
// FMA chains, fold tree, gather, store: BYTE-identical to r8 ->
// scan bit-identical (canary: absmax exactly 0.0009765625).
// =====================================================================
__global__ __launch_bounds__(512, 1)
void rnn_scan(const float* __restrict__ Pre, float* __restrict__ Hout,
              const float* __restrict__ Whh, const float* __restrict__ bhh)
{
  __shared__ float wS[32][DIM];                 // 128 KB
  __shared__ __align__(16) float hbuf[2][DIM];  // 8 KB
  __shared__ float pS[8][8];
  const int b    = blockIdx.x & 7;
  const int p    = blockIdx.x >> 3;      // 0..31
  const int wv   = threadIdx.x >> 6;     // 0..7
  const int lane = threadIdx.x & 63;
  const int fl   = ((lane & 1) << 1) | ((lane >> 1) & 1);  // bitrev2

  const float* PreB = Pre  + (size_t)b * SEQ * DIM;
  float*       HB   = Hout + (size_t)b * SEQ * DIM;

  // stage this WG's 32 weight rows into LDS (coalesced float4)
  for (int i = threadIdx.x; i < 32 * (DIM / 4); i += 512) {
    const int row = i >> 8, c4 = i & 255;
    *(f32x4*)&wS[row][c4 * 4] =
        *(const f32x4*)&Whh[(size_t)(p * 32 + row) * DIM + c4 * 4];
  }
  __syncthreads();

  const bool w0lane = (wv == 0) && (lane < 32);
  const float biasv = w0lane ? bhh[p * 32 + lane] : 0.f;

  for (int t = 0; t < SEQ; ++t) {
    // ---- h-independent hoists: overlap wave0's poll ----
    float pre = 0.f;
    if (w0lane) pre = PreB[(size_t)t * DIM + p * 32 + lane];

    f32x4 wr[4][4];
    if (wv != 0) {
#pragma unroll
      for (int r = 0; r < 4; ++r) {
        wr[r][0] = *(const f32x4*)&wS[wv * 4 + r][  0 + lane * 4];
        wr[r][1] = *(const f32x4*)&wS[wv * 4 + r][256 + lane * 4];
        wr[r][2] = *(const f32x4*)&wS[wv * 4 + r][512 + lane * 4];
        wr[r][3] = *(const f32x4*)&wS[wv * 4 + r][768 + lane * 4];
      }
    }

    if (t > 0) {
      if (wv == 0) {
        const float* hp = HB + (size_t)(t - 1) * DIM;
        const float* q0 = hp +   0 + lane * 4;
        const float* q1 = hp + 256 + lane * 4;
        const float* q2 = hp + 512 + lane * 4;
        const float* q3 = hp + 768 + lane * 4;
        f32x4 m0, m1, m2, m3;
        while (true) {
          f32x4 f0, f1, f2, f3;
          asm volatile(                      // FAST: own-XCD L2 view
            "global_load_dwordx4 %0, %4, off sc0\n\t"
            "global_load_dwordx4 %1, %5, off sc0\n\t"
            "global_load_dwordx4 %2, %6, off sc0\n\t"
            "global_load_dwordx4 %3, %7, off sc0\n\t"
            "s_waitcnt vmcnt(0)"
            : "=&v"(f0), "=&v"(f1), "=&v"(f2), "=&v"(f3)
            : "v"(q0), "v"(q1), "v"(q2), "v"(q3));
          bool gf = true;
#pragma unroll
          for (int j = 0; j < 4; ++j) {
            gf = gf && (__float_as_uint(f0[j]) != 0xFFFFFFFFu)
                    && (__float_as_uint(f1[j]) != 0xFFFFFFFFu)
                    && (__float_as_uint(f2[j]) != 0xFFFFFFFFu)
                    && (__float_as_uint(f3[j]) != 0xFFFFFFFFu);
          }
          if (__all(gf)) { m0 = f0; m1 = f1; m2 = f2; m3 = f3; break; }

          f32x4 s0, s1, s2, s3;
          asm volatile(                      // SLOW: L3 view (always correct)
            "global_load_dwordx4 %0, %4, off sc0 sc1\n\t"
            "global_load_dwordx4 %1, %5, off sc0 sc1\n\t"
            "global_load_dwordx4 %2, %6, off sc0 sc1\n\t"
            "global_load_dwordx4 %3, %7, off sc0 sc1\n\t"
            "s_waitcnt vmcnt(0)"
            : "=&v"(s0), "=&v"(s1), "=&v"(s2), "=&v"(s3)
            : "v"(q0), "v"(q1), "v"(q2), "v"(q3));
          bool gm = true;
#pragma unroll
          for (int j = 0; j < 4; ++j) {
            m0[j] = (__float_as_uint(f0[j]) != 0xFFFFFFFFu) ? f0[j] : s0[j];
            m1[j] = (__float_as_uint(f1[j]) != 0xFFFFFFFFu) ? f1[j] : s1[j];
            m2[j] = (__float_as_uint(f2[j]) != 0xFFFFFFFFu) ? f2[j] : s2[j];
            m3[j] = (__float_as_uint(f3[j]) != 0xFFFFFFFFu) ? f3[j] : s3[j];
            gm = gm && (__float_as_uint(m0[j]) != 0xFFFFFFFFu)
                    && (__float_as_uint(m1[j]) != 0xFFFFFFFFu)
                    && (__float_as_uint(m2[j]) != 0xFFFFFFFFu)
                    && (__float_as_uint(m3[j]) != 0xFFFFFFFFu);
          }
          if (__all(gm)) break;
        }
        *(f32x4*)&hbuf[t & 1][  0 + lane * 4] = m0;
        *(f32x4*)&hbuf[t & 1][256 + lane * 4] = m1;
        *(f32x4*)&hbuf[t & 1][512 + lane * 4] = m2;
        *(f32x4*)&hbuf[t & 1][768 + lane * 4] = m3;
        // wave0 prefetch: issues now, completes under the barrier wait
#pragma unroll
        for (int r = 0; r < 4; ++r) {
          wr[r][0] = *(const f32x4*)&wS[wv * 4 + r][  0 + lane * 4];
          wr[r][1] = *(const f32x4*)&wS[wv * 4 + r][256 + lane * 4];
          wr[r][2] = *(const f32x4*)&wS[wv * 4 + r][512 + lane * 4];
          wr[r][3] = *(const f32x4*)&wS[wv * 4 + r][768 + lane * 4];
        }
      }
      __syncthreads();   // A: hbuf ready
      const f32x4 h0 = *(const f32x4*)&hbuf[t & 1][  0 + lane * 4];
      const f32x4 h1 = *(const f32x4*)&hbuf[t & 1][256 + lane * 4];
      const f32x4 h2 = *(const f32x4*)&hbuf[t & 1][512 + lane * 4];
      const f32x4 h3 = *(const f32x4*)&hbuf[t & 1][768 + lane * 4];
      float acc[4];
#pragma unroll
      for (int r = 0; r < 4; ++r) {
        float a = 0.f;
        a = fmaf(wr[r][0].x, h0.x, fmaf(wr[r][0].y, h0.y,
            fmaf(wr[r][0].z, h0.z, fmaf(wr[r][0].w, h0.w, a))));
        a = fmaf(wr[r][1].x, h1.x, fmaf(wr[r][1].y, h1.y,
            fmaf(wr[r][1].z, h1.z, fmaf(wr[r][1].w, h1.w, a))));
        a = fmaf(wr[r][2].x, h2.x, fmaf(wr[r][2].y, h2.y,
            fmaf(wr[r][2].z, h2.z, fmaf(wr[r][2].w, h2.w, a))));
        a = fmaf(wr[r][3].x, h3.x, fmaf(wr[r][3].y, h3.y,
            fmaf(wr[r][3].z, h3.z, fmaf(wr[r][3].w, h3.w, a))));
        acc[r] = a;
      }
      // fold 4 accs over masks 1,2; finish 4..32 (same tree as r8)
#pragma unroll
      for (int m = 0; m < 2; ++m) {
        const int mask = 1 << m;
        const int nv   = 2 >> m;
        const bool up  = (lane & mask) != 0;
#pragma unroll
        for (int r = 0; r < nv; ++r) {
          const float lo = up ? acc[r + nv] : acc[r];
          const float hi = up ? acc[r] : acc[r + nv];
          acc[r] = lo + __shfl_xor(hi, mask);
        }
      }
#pragma unroll
      for (int off = 4; off < 64; off <<= 1) acc[0] += __shfl_xor(acc[0], off);

      if (lane < 4) pS[wv][fl] = acc[0];
      __syncthreads();   // B: pS ready
    }

    if (w0lane) {
      float s = (t > 0) ? (pre + pS[lane >> 2][lane & 3] + biasv)
                        : (pre + biasv);
      const float v = fast_tanh(s);
      float* dst = HB + (size_t)t * DIM + p * 32 + lane;
      asm volatile(
        "global_store_dword %0, %1, off sc0\n\t"        // fast: own-XCD L2
        "global_store_dword %0, %1, off sc0 sc1"        // slow: through to L3
        :: "v"(dst), "v"(v));
    }
  }
}

// =====================================================================
// Masked softmax, in place, one row per block
// =====================================================================
__global__ __launch_bounds__(256)
void softmax_mask(float* __restrict__ S, const unsigned char* __restrict__ mask)
{
  const size_t row = (size_t)blockIdx.y * gridDim.x + blockIdx.x;
  float* p = S + row * SEQ;
  const unsigned char* mrow = mask + row * SEQ;
  __shared__ float buf[SEQ];
  __shared__ float red[4];
  const int tid = threadIdx.x, lane = tid & 63, wv = tid >> 6;

  float mx = -1e30f;
  for (int i = tid; i < SEQ; i += 256) {
    const float v = mrow[i] ? -1e9f : p[i];
    buf[i] = v;
    mx = fmaxf(mx, v);
  }
#pragma unroll
  for (int off = 1; off < 64; off <<= 1) mx = fmaxf(mx, __shfl_xor(mx, off));
  if (lane == 0) red[wv] = mx;
  __syncthreads();
  mx = fmaxf(fmaxf(red[0], red[1]), fmaxf(red[2], red[3]));

  float s = 0.f;
  for (int i = tid; i < SEQ; i += 256) {
    const float e = __expf(buf[i] - mx);
    buf[i] = e;
    s += e;
  }
#pragma unroll
  for (int off = 1; off < 64; off <<= 1) s += __shfl_xor(s, off);
  __syncthreads();
  if (lane == 0) red[wv] = s;
  __syncthreads();
  s = red[0] + red[1] + red[2] + red[3];
  const float inv = 1.f / s;
  for (int i = tid; i < SEQ; i += 256) p[i] = buf[i] * inv;
}

// =====================================================================
extern "C" void kernel_launch(void* const* d_in, const int* in_sizes, int n_in,
                              void* d_out, int out_size, void* d_ws, size_t ws_size,
                              hipStream_t stream)
{
  (void)in_sizes; (void)n_in; (void)out_size;
  const unsigned char* mask = (const unsigned char*)d_in[0];
  const float* reps = (const float*)d_in[1];
  const float* Wih  = (const float*)d_in[2];
  const float* Whh  = (const float*)d_in[3];
  const float* bih  = (const float*)d_in[4];
  const float* bhh  = (const float*)d_in[5];
  const float* Wq   = (const float*)d_in[6];
  const float* bq   = (const float*)d_in[7];
  const float* Wk   = (const float*)d_in[8];
  const float* bk   = (const float*)d_in[9];
  const float* Wv   = (const float*)d_in[10];
  const float* bv   = (const float*)d_in[11];
  const float* Wo   = (const float*)d_in[12];
  const float* bo   = (const float*)d_in[13];
  float* out = (float*)d_out;

  char* ws = (char*)d_ws;
  float* Hb = (float*)(ws);
  float* Qb = (float*)(ws + ((size_t)64  << 20));
  float* Kb = (float*)(ws + ((size_t)128 << 20));
  float* Vb = (float*)(ws + ((size_t)192 << 20));
  float* Sb = (float*)(ws + ((size_t)256 << 20));
  const size_t needFull = ((size_t)256 << 20) + (size_t)BATCH * SEQ * SEQ * 4;
  const bool fullS = ws_size >= needFull;
  const size_t hBytes = (size_t)BATCH * SEQ * DIM * 4;

  const int M1 = BATCH * SEQ;
  const float scale = 0.03125f;
  const dim3 blk(256);
  const long long sSD = (long long)SEQ * DIM;
  const long long sSS = (long long)SEQ * SEQ;

  const float* X = reps;
  for (int l = 0; l < NLAYER; ++l) {
    const size_t wof = (size_t)l * DIM * DIM;
    const size_t bof = (size_t)l * DIM;
    float* Y = (l == NLAYER - 1) ? out : Qb;

    hipMemsetAsync(Hb, 0xFF, hBytes, stream);
    gemm_bf16x3<1><<<dim3(M1/128, DIM/128, 1), blk, 0, stream>>>(
        X, Wih + wof, bih + bof, Kb, M1, DIM, DIM, 1.f, 0, 0, 0);
    rnn_scan<<<dim3(256), dim3(512), 0, stream>>>(Kb, Hb, Whh + wof, bhh + bof);

    gemm_bf16x3<1><<<dim3(M1/128, DIM/128, 1), blk, 0, stream>>>(
        Hb, Wq + wof, bq + bof, Qb, M1, DIM, DIM, 1.f, 0, 0, 0);
    gemm_bf16x3<1><<<dim3(M1/128, DIM/128, 1), blk, 0, stream>>>(
        Hb, Wk + wof, bk + bof, Kb, M1, DIM, DIM, 1.f, 0, 0, 0);
    gemm_bf16x3<1><<<dim3(M1/128, DIM/128, 1), blk, 0, stream>>>(
        Hb, Wv + wof, bv + bof, Vb, M1, DIM, DIM, 1.f, 0, 0, 0);

    if (fullS) {
      gemm_bf16x3<1><<<dim3(SEQ/128, SEQ/128, BATCH), blk, 0, stream>>>(
          Qb, Kb, nullptr, Sb, SEQ, SEQ, DIM, scale, sSD, sSD, sSS);
      softmax_mask<<<dim3(SEQ, BATCH), blk, 0, stream>>>(Sb, mask);
      gemm_bf16x3<0><<<dim3(SEQ/128, DIM/128, BATCH), blk, 0, stream>>>(
          Sb, Vb, nullptr, Hb, SEQ, DIM, SEQ, 1.f, sSS, sSD, sSD);
    } else {
      for (int bb = 0; bb < BATCH; ++bb) {
        gemm_bf16x3<1><<<dim3(SEQ/128, SEQ/128, 1), blk, 0, stream>>>(
            Qb + (size_t)bb * sSD, Kb + (size_t)bb * sSD, nullptr, Sb,
            SEQ, SEQ, DIM, scale, 0, 0, 0);
        softmax_mask<<<dim3(SEQ, 1), blk, 0, stream>>>(Sb, mask + (size_t)bb * sSS);
        gemm_bf16x3<0><<<dim3(SEQ/128, DIM/128, 1), blk, 0, stream>>>(
            Sb, Vb + (size_t)bb * sSD, nullptr, Hb + (size_t)bb * sSD,
            SEQ, DIM, SEQ, 1.f, 0, 0, 0);
      }
    }
    gemm_bf16x3<1><<<dim3(M1/128, DIM/128, 1), blk, 0, stream>>>(
        Hb, Wo + wof, bo + bof, Y, M1, DIM, DIM, 1.f, 0, 0, 0);
    X = Y;
  }
}

// Round 12
// 10838.531 us; speedup vs baseline: 2.5200x; 1.0481x over previous
//
#include <hip/hip_runtime.h>
#include <hip/hip_bf16.h>

#define BATCH 8
#define SEQ   2048
#define DIM   1024
#define NLAYER 2

typedef float  f32x4 __attribute__((ext_vector_type(4)));
typedef short  s16x8 __attribute__((ext_vector_type(8)));
typedef unsigned short u16x4 __attribute__((ext_vector_type(4)));

// =====================================================================
// bf16x3 split-precision MFMA GEMM.
// r12 change: cheap split. hi = HW RNE cast (v_cvt_pk-able), lo =
// truncation of the residual (1 sub + 1 shift). Was ~10 VALU/elem
// (manual integer RNE x2), now ~4 — the GEMM was split-VALU-bound
// (~320 cy staging vs ~230 cy MFMA per K-step).
// =====================================================================
__device__ __forceinline__ void split_bf16(float x, unsigned short& hi, unsigned short& lo) {
  const __hip_bfloat16 hb = __float2bfloat16(x);          // HW RNE
  hi = *reinterpret_cast<const unsigned short*>(&hb);
  const float hf = __bfloat162float(hb);                  // shl 16
  lo = (unsigned short)(__float_as_uint(x - hf) >> 16);   // truncate residual
}

template<int TRANSB>
__global__ __launch_bounds__(256)
void gemm_bf16x3(const float* __restrict__ A, const float* __restrict__ B,
                 const float* __restrict__ bias, float* __restrict__ C,
                 int M, int N, int K, float alpha,
                 long long strideA, long long strideB, long long strideC)
{
  constexpr int LK = 40;
  __shared__ unsigned short Ah[128 * LK], Al[128 * LK];
  __shared__ unsigned short Bh[128 * LK], Bl[128 * LK];

  const int z = blockIdx.z;
  A += (size_t)z * strideA;
  B += (size_t)z * strideB;
  C += (size_t)z * strideC;

  const int tid  = threadIdx.x;
  const int row0 = blockIdx.x * 128;
  const int col0 = blockIdx.y * 128;
  const int w    = tid >> 6;
  const int lane = tid & 63;
  const int m0   = (w >> 1) * 64;
  const int n0   = (w & 1) * 64;
  const int half = lane >> 4;
  const int mr   = lane & 15;

  f32x4 acc[4][4];
#pragma unroll
  for (int i = 0; i < 4; ++i)
#pragma unroll
    for (int j = 0; j < 4; ++j) acc[i][j] = (f32x4){0.f, 0.f, 0.f, 0.f};

  for (int k0 = 0; k0 < K; k0 += 32) {
    __syncthreads();
    {
      const int r = tid >> 3, c4 = tid & 7;
#pragma unroll
      for (int rep = 0; rep < 4; ++rep) {
        const int row = r + rep * 32;
        const float4 v = *(const float4*)&A[(size_t)(row0 + row) * K + k0 + c4 * 4];
        unsigned short h0,h1,h2,h3,l0,l1,l2,l3;
        split_bf16(v.x, h0, l0); split_bf16(v.y, h1, l1);
        split_bf16(v.z, h2, l2); split_bf16(v.w, h3, l3);
        *(u16x4*)&Ah[row * LK + c4 * 4] = (u16x4){h0, h1, h2, h3};
        *(u16x4*)&Al[row * LK + c4 * 4] = (u16x4){l0, l1, l2, l3};
      }
    }
    if (TRANSB) {
      const int r = tid >> 3, c4 = tid & 7;
#pragma unroll
      for (int rep = 0; rep < 4; ++rep) {
        const int row = r + rep * 32;
        const float4 v = *(const float4*)&B[(size_t)(col0 + row) * K + k0 + c4 * 4];
        unsigned short h0,h1,h2,h3,l0,l1,l2,l3;
        split_bf16(v.x, h0, l0); split_bf16(v.y, h1, l1);
        split_bf16(v.z, h2, l2); split_bf16(v.w, h3, l3);
        *(u16x4*)&Bh[row * LK + c4 * 4] = (u16x4){h0, h1, h2, h3};
        *(u16x4*)&Bl[row * LK + c4 * 4] = (u16x4){l0, l1, l2, l3};
      }
    } else {
      const int kk8 = tid >> 5, n4 = tid & 31;
#pragma unroll
      for (int rep = 0; rep < 4; ++rep) {
        const int kk = kk8 + rep * 8;
        const float4 v = *(const float4*)&B[(size_t)(k0 + kk) * N + col0 + n4 * 4];
        unsigned short h, l;
        split_bf16(v.x, h, l); Bh[(n4*4+0)*LK + kk] = h; Bl[(n4*4+0)*LK + kk] = l;
        split_bf16(v.y, h, l); Bh[(n4*4+1)*LK + kk] = h; Bl[(n4*4+1)*LK + kk] = l;
        split_bf16(v.z, h, l); Bh[(n4*4+2)*LK + kk] = h; Bl[(n4*4+2)*LK + kk] = l;
        split_bf16(v.w, h, l); Bh[(n4*4+3)*LK + kk] = h; Bl[(n4*4+3)*LK + kk] = l;
      }
    }
    __syncthreads();

    s16x8 ah[4], al[4], bh[4], bl[4];
#pragma unroll
    for (int i = 0; i < 4; ++i) {
      ah[i] = *(const s16x8*)&Ah[(m0 + i*16 + mr) * LK + half * 8];
      al[i] = *(const s16x8*)&Al[(m0 + i*16 + mr) * LK + half * 8];
      bh[i] = *(const s16x8*)&Bh[(n0 + i*16 + mr) * LK + half * 8];
      bl[i] = *(const s16x8*)&Bl[(n0 + i*16 + mr) * LK + half * 8];
    }
#pragma unroll
    for (int i = 0; i < 4; ++i)
#pragma unroll
      for (int j = 0; j < 4; ++j) {
        acc[i][j] = __builtin_amdgcn_mfma_f32_16x16x32_bf16(ah[i], bh[j], acc[i][j], 0, 0, 0);
        acc[i][j] = __builtin_amdgcn_mfma_f32_16x16x32_bf16(ah[i], bl[j], acc[i][j], 0, 0, 0);
        acc[i][j] = __builtin_amdgcn_mfma_f32_16x16x32_bf16(al[i], bh[j], acc[i][j], 0, 0, 0);
      }
  }

#pragma unroll
  for (int j = 0; j < 4; ++j) {
    const int col = col0 + n0 + j * 16 + mr;
    const float bb = bias ? bias[col] : 0.f;
#pragma unroll
    for (int i = 0; i < 4; ++i) {
#pragma unroll
      for (int q = 0; q < 4; ++q) {
        const int row = row0 + m0 + i * 16 + half * 4 + q;
        C[(size_t)row * N + col] = fmaf(alpha, acc[i][j][q], bb);
      }
    }
  }
}

// =====================================================================
// tanh without an OCML call (abs err ~1e-7)
// =====================================================================
__device__ __forceinline__ float fast_tanh(float x) {
  const float a = fabsf(x);
  const float e = __expf(2.0f * a);
  const float t = 1.0f - 2.0f / (e + 1.0f);
  return copysignf(t, x);
}

// =====================================================================
// RNN scan v9 (UNCHANGED from r11 — best validated: 3.84 ms/scan).
// wave0 poll + LDS broadcast + 2 barriers + wave0 coalesced store;
// h-independent work (weight frags, pre) hoisted ahead of the barrier.
// =====================================================================
__global__ __launch_bounds__(512, 1)
void rnn_scan(const float* __restrict__ Pre, float* __restrict__ Hout,
              const float* __restrict__ Whh, const float* __restrict__ bhh)
{
  __shared__ float wS[32][DIM];                 // 128 KB
  __shared__ __align__(16) float hbuf[2][DIM];  // 8 KB
  __shared__ float pS[8][8];
  const int b    = blockIdx.x & 7;
  const int p    = blockIdx.x >> 3;      // 0..31
  const int wv   = threadIdx.x >> 6;     // 0..7
  const int lane = threadIdx.x & 63;
  const int fl   = ((lane & 1) << 1) | ((lane >> 1) & 1);  // bitrev2

  const float* PreB = Pre  + (size_t)b * SEQ * DIM;
  float*       HB   = Hout + (size_t)b * SEQ * DIM;

  for (int i = threadIdx.x; i < 32 * (DIM / 4); i += 512) {
    const int row = i >> 8, c4 = i & 255;
    *(f32x4*)&wS[row][c4 * 4] =
        *(const f32x4*)&Whh[(size_t)(p * 32 + row) * DIM + c4 * 4];
  }
  __syncthreads();

  const bool w0lane = (wv == 0) && (lane < 32);
  const float biasv = w0lane ? bhh[p * 32 + lane] : 0.f;

  for (int t = 0; t < SEQ; ++t) {
    float pre = 0.f;
    if (w0lane) pre = PreB[(size_t)t * DIM + p * 32 + lane];

    f32x4 wr[4][4];
    if (wv != 0) {
#pragma unroll
      for (int r = 0; r < 4; ++r) {
        wr[r][0] = *(const f32x4*)&wS[wv * 4 + r][  0 + lane * 4];
        wr[r][1] = *(const f32x4*)&wS[wv * 4 + r][256 + lane * 4];
        wr[r][2] = *(const f32x4*)&wS[wv * 4 + r][512 + lane * 4];
        wr[r][3] = *(const f32x4*)&wS[wv * 4 + r][768 + lane * 4];
      }
    }

    if (t > 0) {
      if (wv == 0) {
        const float* hp = HB + (size_t)(t - 1) * DIM;
        const float* q0 = hp +   0 + lane * 4;
        const float* q1 = hp + 256 + lane * 4;
        const float* q2 = hp + 512 + lane * 4;
        const float* q3 = hp + 768 + lane * 4;
        f32x4 m0, m1, m2, m3;
        while (true) {
          f32x4 f0, f1, f2, f3;
          asm volatile(                      // FAST: own-XCD L2 view
            "global_load_dwordx4 %0, %4, off sc0\n\t"
            "global_load_dwordx4 %1, %5, off sc0\n\t"
            "global_load_dwordx4 %2, %6, off sc0\n\t"
            "global_load_dwordx4 %3, %7, off sc0\n\t"
            "s_waitcnt vmcnt(0)"
            : "=&v"(f0), "=&v"(f1), "=&v"(f2), "=&v"(f3)
            : "v"(q0), "v"(q1), "v"(q2), "v"(q3));
          bool gf = true;
#pragma unroll
          for (int j = 0; j < 4; ++j) {
            gf = gf && (__float_as_uint(f0[j]) != 0xFFFFFFFFu)
                    && (__float_as_uint(f1[j]) != 0xFFFFFFFFu)
                    && (__float_as_uint(f2[j]) != 0xFFFFFFFFu)
                    && (__float_as_uint(f3[j]) != 0xFFFFFFFFu);
          }
          if (__all(gf)) { m0 = f0; m1 = f1; m2 = f2; m3 = f3; break; }

          f32x4 s0, s1, s2, s3;
          asm volatile(                      // SLOW: L3 view (always correct)
            "global_load_dwordx4 %0, %4, off sc0 sc1\n\t"
            "global_load_dwordx4 %1, %5, off sc0 sc1\n\t"
            "global_load_dwordx4 %2, %6, off sc0 sc1\n\t"
            "global_load_dwordx4 %3, %7, off sc0 sc1\n\t"
            "s_waitcnt vmcnt(0)"
            : "=&v"(s0), "=&v"(s1), "=&v"(s2), "=&v"(s3)
            : "v"(q0), "v"(q1), "v"(q2), "v"(q3));
          bool gm = true;
#pragma unroll
          for (int j = 0; j < 4; ++j) {
            m0[j] = (__float_as_uint(f0[j]) != 0xFFFFFFFFu) ? f0[j] : s0[j];
            m1[j] = (__float_as_uint(f1[j]) != 0xFFFFFFFFu) ? f1[j] : s1[j];
            m2[j] = (__float_as_uint(f2[j]) != 0xFFFFFFFFu) ? f2[j] : s2[j];
            m3[j] = (__float_as_uint(f3[j]) != 0xFFFFFFFFu) ? f3[j] : s3[j];
            gm = gm && (__float_as_uint(m0[j]) != 0xFFFFFFFFu)
                    && (__float_as_uint(m1[j]) != 0xFFFFFFFFu)
                    && (__float_as_uint(m2[j]) != 0xFFFFFFFFu)
                    && (__float_as_uint(m3[j]) != 0xFFFFFFFFu);
          }
          if (__all(gm)) break;
        }
        *(f32x4*)&hbuf[t & 1][  0 + lane * 4] = m0;
        *(f32x4*)&hbuf[t & 1][256 + lane * 4] = m1;
        *(f32x4*)&hbuf[t & 1][512 + lane * 4] = m2;
        *(f32x4*)&hbuf[t & 1][768 + lane * 4] = m3;
#pragma unroll
        for (int r = 0; r < 4; ++r) {
          wr[r][0] = *(const f32x4*)&wS[wv * 4 + r][  0 + lane * 4];
          wr[r][1] = *(const f32x4*)&wS[wv * 4 + r][256 + lane * 4];
          wr[r][2] = *(const f32x4*)&wS[wv * 4 + r][512 + lane * 4];
          wr[r][3] = *(const f32x4*)&wS[wv * 4 + r][768 + lane * 4];
        }
      }
      __syncthreads();   // A: hbuf ready
      const f32x4 h0 = *(const f32x4*)&hbuf[t & 1][  0 + lane * 4];
      const f32x4 h1 = *(const f32x4*)&hbuf[t & 1][256 + lane * 4];
      const f32x4 h2 = *(const f32x4*)&hbuf[t & 1][512 + lane * 4];
      const f32x4 h3 = *(const f32x4*)&hbuf[t & 1][768 + lane * 4];
      float acc[4];
#pragma unroll
      for (int r = 0; r < 4; ++r) {
        float a = 0.f;
        a = fmaf(wr[r][0].x, h0.x, fmaf(wr[r][0].y, h0.y,
            fmaf(wr[r][0].z, h0.z, fmaf(wr[r][0].w, h0.w, a))));
        a = fmaf(wr[r][1].x, h1.x, fmaf(wr[r][1].y, h1.y,
            fmaf(wr[r][1].z, h1.z, fmaf(wr[r][1].w, h1.w, a))));
        a = fmaf(wr[r][2].x, h2.x, fmaf(wr[r][2].y, h2.y,
            fmaf(wr[r][2].z, h2.z, fmaf(wr[r][2].w, h2.w, a))));
        a = fmaf(wr[r][3].x, h3.x, fmaf(wr[r][3].y, h3.y,
            fmaf(wr[r][3].z, h3.z, fmaf(wr[r][3].w, h3.w, a))));
        acc[r] = a;
      }
#pragma unroll
      for (int m = 0; m < 2; ++m) {
        const int mask = 1 << m;
        const int nv   = 2 >> m;
        const bool up  = (lane & mask) != 0;
#pragma unroll
        for (int r = 0; r < nv; ++r) {
          const float lo = up ? acc[r + nv] : acc[r];
          const float hi = up ? acc[r] : acc[r + nv];
          acc[r] = lo + __shfl_xor(hi, mask);
        }
      }
#pragma unroll
      for (int off = 4; off < 64; off <<= 1) acc[0] += __shfl_xor(acc[0], off);

      if (lane < 4) pS[wv][fl] = acc[0];
      __syncthreads();   // B: pS ready
    }

    if (w0lane) {
      float s = (t > 0) ? (pre + pS[lane >> 2][lane & 3] + biasv)
                        : (pre + biasv);
      const float v = fast_tanh(s);
      float* dst = HB + (size_t)t * DIM + p * 32 + lane;
      asm volatile(
        "global_store_dword %0, %1, off sc0\n\t"
        "global_store_dword %0, %1, off sc0 sc1"
        :: "v"(dst), "v"(v));
    }
  }
}

// =====================================================================
// Masked softmax, in place, one row per block
// =====================================================================
__global__ __launch_bounds__(256)
void softmax_mask(float* __restrict__ S, const unsigned char* __restrict__ mask)
{
  const size_t row = (size_t)blockIdx.y * gridDim.x + blockIdx.x;
  float* p = S + row * SEQ;
  const unsigned char* mrow = mask + row * SEQ;
  __shared__ float buf[SEQ];
  __shared__ float red[4];
  const int tid = threadIdx.x, lane = tid & 63, wv = tid >> 6;

  float mx = -1e30f;
  for (int i = tid; i < SEQ; i += 256) {
    const float v = mrow[i] ? -1e9f : p[i];
    buf[i] = v;
    mx = fmaxf(mx, v);
  }
#pragma unroll
  for (int off = 1; off < 64; off <<= 1) mx = fmaxf(mx, __shfl_xor(mx, off));
  if (lane == 0) red[wv] = mx;
  __syncthreads();
  mx = fmaxf(fmaxf(red[0], red[1]), fmaxf(red[2], red[3]));

  float s = 0.f;
  for (int i = tid; i < SEQ; i += 256) {
    const float e = __expf(buf[i] - mx);
    buf[i] = e;
    s += e;
  }
#pragma unroll
  for (int off = 1; off < 64; off <<= 1) s += __shfl_xor(s, off);
  __syncthreads();
  if (lane == 0) red[wv] = s;
  __syncthreads();
  s = red[0] + red[1] + red[2] + red[3];
  const float inv = 1.f / s;
  for (int i = tid; i < SEQ; i += 256) p[i] = buf[i] * inv;
}

// =====================================================================
extern "C" void kernel_launch(void* const* d_in, const int* in_sizes, int n_in,
                              void* d_out, int out_size, void* d_ws, size_t ws_size,
                              hipStream_t stream)
{
  (void)in_sizes; (void)n_in; (void)out_size;
  const unsigned char* mask = (const unsigned char*)d_in[0];
  const float* reps = (const float*)d_in[1];
  const float* Wih  = (const float*)d_in[2];
  const float* Whh  = (const float*)d_in[3];
  const float* bih  = (const float*)d_in[4];
  const float* bhh  = (const float*)d_in[5];
  const float* Wq   = (const float*)d_in[6];
  const float* bq   = (const float*)d_in[7];
  const float* Wk   = (const float*)d_in[8];
  const float* bk   = (const float*)d_in[9];
  const float* Wv   = (const float*)d_in[10];
  const float* bv   = (const float*)d_in[11];
  const float* Wo   = (const float*)d_in[12];
  const float* bo   = (const float*)d_in[13];
  float* out = (float*)d_out;

  char* ws = (char*)d_ws;
  float* Hb = (float*)(ws);
  float* Qb = (float*)(ws + ((size_t)64  << 20));
  float* Kb = (float*)(ws + ((size_t)128 << 20));
  float* Vb = (float*)(ws + ((size_t)192 << 20));
  float* Sb = (float*)(ws + ((size_t)256 << 20));
  const size_t needFull = ((size_t)256 << 20) + (size_t)BATCH * SEQ * SEQ * 4;
  const bool fullS = ws_size >= needFull;
  const size_t hBytes = (size_t)BATCH * SEQ * DIM * 4;

  const int M1 = BATCH * SEQ;
  const float scale = 0.03125f;
  const dim3 blk(256);
  const long long sSD = (long long)SEQ * DIM;
  const long long sSS = (long long)SEQ * SEQ;

  const float* X = reps;
  for (int l = 0; l < NLAYER; ++l) {
    const size_t wof = (size_t)l * DIM * DIM;
    const size_t bof = (size_t)l * DIM;
    float* Y = (l == NLAYER - 1) ? out : Qb;

    hipMemsetAsync(Hb, 0xFF, hBytes, stream);
    gemm_bf16x3<1><<<dim3(M1/128, DIM/128, 1), blk, 0, stream>>>(
        X, Wih + wof, bih + bof, Kb, M1, DIM, DIM, 1.f, 0, 0, 0);
    rnn_scan<<<dim3(256), dim3(512), 0, stream>>>(Kb, Hb, Whh + wof, bhh + bof);

    gemm_bf16x3<1><<<dim3(M1/128, DIM/128, 1), blk, 0, stream>>>(
        Hb, Wq + wof, bq + bof, Qb, M1, DIM, DIM, 1.f, 0, 0, 0);
    gemm_bf16x3<1><<<dim3(M1/128, DIM/128, 1), blk, 0, stream>>>(
        Hb, Wk + wof, bk + bof, Kb, M1, DIM, DIM, 1.f, 0, 0, 0);
    gemm_bf16x3<1><<<dim3(M1/128, DIM/128, 1), blk, 0, stream>>>(
        Hb, Wv + wof, bv + bof, Vb, M1, DIM, DIM, 1.f, 0, 0, 0);

    if (fullS) {
      gemm_bf16x3<1><<<dim3(SEQ/128, SEQ/128, BATCH), blk, 0, stream>>>(
          Qb, Kb, nullptr, Sb, SEQ, SEQ, DIM, scale, sSD, sSD, sSS);
      softmax_mask<<<dim3(SEQ, BATCH), blk, 0, stream>>>(Sb, mask);
      gemm_bf16x3<0><<<dim3(SEQ/128, DIM/128, BATCH), blk, 0, stream>>>(
          Sb, Vb, nullptr, Hb, SEQ, DIM, SEQ, 1.f, sSS, sSD, sSD);
    } else {
      for (int bb = 0; bb < BATCH; ++bb) {
        gemm_bf16x3<1><<<dim3(SEQ/128, SEQ/128, 1), blk, 0, stream>>>(
            Qb + (size_t)bb * sSD, Kb + (size_t)bb * sSD, nullptr, Sb,
            SEQ, SEQ, DIM, scale, 0, 0, 0);
        softmax_mask<<<dim3(SEQ, 1), blk, 0, stream>>>(Sb, mask + (size_t)bb * sSS);
        gemm_bf16x3<0><<<dim3(SEQ/128, DIM/128, 1), blk, 0, stream>>>(
            Sb, Vb + (size_t)bb * sSD, nullptr, Hb + (size_t)bb * sSD,
            SEQ, DIM, SEQ, 1.f, 0, 0, 0);
      }
    }
    gemm_bf16x3<1><<<dim3(M1/128, DIM/128, 1), blk, 0, stream>>>(
        Hb, Wo + wof, bo + bof, Y, M1, DIM, DIM, 1.f, 0, 0, 0);
    X = Y;
  }
}

// Round 14
// 10707.516 us; speedup vs baseline: 2.5509x; 1.0122x over previous
//
#include <hip/hip_runtime.h>
#include <hip/hip_bf16.h>

#define BATCH 8
#define SEQ   2048
#define DIM   1024
#define NLAYER 2

typedef float  f32x4 __attribute__((ext_vector_type(4)));
typedef short  s16x8 __attribute__((ext_vector_type(8)));
typedef unsigned short u16x4 __attribute__((ext_vector_type(4)));

// =====================================================================
// cheap bf16 split (r12): hi = HW RNE cast, lo = truncated residual
// =====================================================================
__device__ __forceinline__ void split_bf16(float x, unsigned short& hi, unsigned short& lo) {
  const __hip_bfloat16 hb = __float2bfloat16(x);          // HW RNE
  hi = *reinterpret_cast<const unsigned short*>(&hb);
  const float hf = __bfloat162float(hb);
  lo = (unsigned short)(__float_as_uint(x - hf) >> 16);   // truncate residual
}

// =====================================================================
// one-shot weight splitter: W (f32, n=DIM*DIM) -> Wh, Wl (u16 planes).
// Same split_bf16 as the GEMM staging -> downstream results BIT-identical.
// =====================================================================
__global__ __launch_bounds__(256)
void split_mat(const float* __restrict__ W, unsigned short* __restrict__ Wh,
               unsigned short* __restrict__ Wl)
{
  const int i = (blockIdx.x * 256 + threadIdx.x) * 4;
  const float4 v = *(const float4*)&W[i];
  unsigned short h0,h1,h2,h3,l0,l1,l2,l3;
  split_bf16(v.x, h0, l0); split_bf16(v.y, h1, l1);
  split_bf16(v.z, h2, l2); split_bf16(v.w, h3, l3);
  *(u16x4*)&Wh[i] = (u16x4){h0, h1, h2, h3};
  *(u16x4*)&Wl[i] = (u16x4){l0, l1, l2, l3};
}

// =====================================================================
// bf16x3 split-precision MFMA GEMM (r12, unchanged) — A,B split on the fly
// =====================================================================
template<int TRANSB>
__global__ __launch_bounds__(256)
void gemm_bf16x3(const float* __restrict__ A, const float* __restrict__ B,
                 const float* __restrict__ bias, float* __restrict__ C,
                 int M, int N, int K, float alpha,
                 long long strideA, long long strideB, long long strideC)
{
  constexpr int LK = 40;
  __shared__ unsigned short Ah[128 * LK], Al[128 * LK];
  __shared__ unsigned short Bh[128 * LK], Bl[128 * LK];

  const int z = blockIdx.z;
  A += (size_t)z * strideA;
  B += (size_t)z * strideB;
  C += (size_t)z * strideC;

  const int tid  = threadIdx.x;
  const int row0 = blockIdx.x * 128;
  const int col0 = blockIdx.y * 128;
  const int w    = tid >> 6;
  const int lane = tid & 63;
  const int m0   = (w >> 1) * 64;
  const int n0   = (w & 1) * 64;
  const int half = lane >> 4;
  const int mr   = lane & 15;

  f32x4 acc[4][4];
#pragma unroll
  for (int i = 0; i < 4; ++i)
#pragma unroll
    for (int j = 0; j < 4; ++j) acc[i][j] = (f32x4){0.f, 0.f, 0.f, 0.f};

  for (int k0 = 0; k0 < K; k0 += 32) {
    __syncthreads();
    {
      const int r = tid >> 3, c4 = tid & 7;
#pragma unroll
      for (int rep = 0; rep < 4; ++rep) {
        const int row = r + rep * 32;
        const float4 v = *(const float4*)&A[(size_t)(row0 + row) * K + k0 + c4 * 4];
        unsigned short h0,h1,h2,h3,l0,l1,l2,l3;
        split_bf16(v.x, h0, l0); split_bf16(v.y, h1, l1);
        split_bf16(v.z, h2, l2); split_bf16(v.w, h3, l3);
        *(u16x4*)&Ah[row * LK + c4 * 4] = (u16x4){h0, h1, h2, h3};
        *(u16x4*)&Al[row * LK + c4 * 4] = (u16x4){l0, l1, l2, l3};
      }
    }
    if (TRANSB) {
      const int r = tid >> 3, c4 = tid & 7;
#pragma unroll
      for (int rep = 0; rep < 4; ++rep) {
        const int row = r + rep * 32;
        const float4 v = *(const float4*)&B[(size_t)(col0 + row) * K + k0 + c4 * 4];
        unsigned short h0,h1,h2,h3,l0,l1,l2,l3;
        split_bf16(v.x, h0, l0); split_bf16(v.y, h1, l1);
        split_bf16(v.z, h2, l2); split_bf16(v.w, h3, l3);
        *(u16x4*)&Bh[row * LK + c4 * 4] = (u16x4){h0, h1, h2, h3};
        *(u16x4*)&Bl[row * LK + c4 * 4] = (u16x4){l0, l1, l2, l3};
      }
    } else {
      const int kk8 = tid >> 5, n4 = tid & 31;
#pragma unroll
      for (int rep = 0; rep < 4; ++rep) {
        const int kk = kk8 + rep * 8;
        const float4 v = *(const float4*)&B[(size_t)(k0 + kk) * N + col0 + n4 * 4];
        unsigned short h, l;
        split_bf16(v.x, h, l); Bh[(n4*4+0)*LK + kk] = h; Bl[(n4*4+0)*LK + kk] = l;
        split_bf16(v.y, h, l); Bh[(n4*4+1)*LK + kk] = h; Bl[(n4*4+1)*LK + kk] = l;
        split_bf16(v.z, h, l); Bh[(n4*4+2)*LK + kk] = h; Bl[(n4*4+2)*LK + kk] = l;
        split_bf16(v.w, h, l); Bh[(n4*4+3)*LK + kk] = h; Bl[(n4*4+3)*LK + kk] = l;
      }
    }
    __syncthreads();

    s16x8 ah[4], al[4], bh[4], bl[4];
#pragma unroll
    for (int i = 0; i < 4; ++i) {
      ah[i] = *(const s16x8*)&Ah[(m0 + i*16 + mr) * LK + half * 8];
      al[i] = *(const s16x8*)&Al[(m0 + i*16 + mr) * LK + half * 8];
      bh[i] = *(const s16x8*)&Bh[(n0 + i*16 + mr) * LK + half * 8];
      bl[i] = *(const s16x8*)&Bl[(n0 + i*16 + mr) * LK + half * 8];
    }
#pragma unroll
    for (int i = 0; i < 4; ++i)
#pragma unroll
      for (int j = 0; j < 4; ++j) {
        acc[i][j] = __builtin_amdgcn_mfma_f32_16x16x32_bf16(ah[i], bh[j], acc[i][j], 0, 0, 0);
        acc[i][j] = __builtin_amdgcn_mfma_f32_16x16x32_bf16(ah[i], bl[j], acc[i][j], 0, 0, 0);
        acc[i][j] = __builtin_amdgcn_mfma_f32_16x16x32_bf16(al[i], bh[j], acc[i][j], 0, 0, 0);
      }
  }

#pragma unroll
  for (int j = 0; j < 4; ++j) {
    const int col = col0 + n0 + j * 16 + mr;
    const float bb = bias ? bias[col] : 0.f;
#pragma unroll
    for (int i = 0; i < 4; ++i) {
#pragma unroll
      for (int q = 0; q < 4; ++q) {
        const int row = row0 + m0 + i * 16 + half * 4 + q;
        C[(size_t)row * N + col] = fmaf(alpha, acc[i][j][q], bb);
      }
    }
  }
}

// =====================================================================
// GEMM with PRE-SPLIT B (N x K weights): B-staging is pure load->LDS,
// zero split VALU. A side / MFMA / epilogue identical to gemm_bf16x3
// (pre-split values come from the same split_bf16 -> BIT-identical C).
// =====================================================================
__global__ __launch_bounds__(256)
void gemm_bsplit(const float* __restrict__ A,
                 const unsigned short* __restrict__ Bhg,
                 const unsigned short* __restrict__ Blg,
                 const float* __restrict__ bias, float* __restrict__ C,
                 int M, int N, int K, float alpha)
{
  constexpr int LK = 40;
  __shared__ unsigned short Ah[128 * LK], Al[128 * LK];
  __shared__ unsigned short Bh[128 * LK], Bl[128 * LK];

  const int tid  = threadIdx.x;
  const int row0 = blockIdx.x * 128;
  const int col0 = blockIdx.y * 128;
  const int w    = tid >> 6;
  const int lane = tid & 63;
  const int m0   = (w >> 1) * 64;
  const int n0   = (w & 1) * 64;
  const int half = lane >> 4;
  const int mr   = lane & 15;

  f32x4 acc[4][4];
#pragma unroll
  for (int i = 0; i < 4; ++i)
#pragma unroll
    for (int j = 0; j < 4; ++j) acc[i][j] = (f32x4){0.f, 0.f, 0.f, 0.f};

  for (int k0 = 0; k0 < K; k0 += 32) {
    __syncthreads();
    {  // A tile: split on the fly (activations)
      const int r = tid >> 3, c4 = tid & 7;
#pragma unroll
      for (int rep = 0; rep < 4; ++rep) {
        const int row = r + rep * 32;
        const float4 v = *(const float4*)&A[(size_t)(row0 + row) * K + k0 + c4 * 4];
        unsigned short h0,h1,h2,h3,l0,l1,l2,l3;
        split_bf16(v.x, h0, l0); split_bf16(v.y, h1, l1);
        split_bf16(v.z, h2, l2); split_bf16(v.w, h3, l3);
        *(u16x4*)&Ah[row * LK + c4 * 4] = (u16x4){h0, h1, h2, h3};
        *(u16x4*)&Al[row * LK + c4 * 4] = (u16x4){l0, l1, l2, l3};
      }
    }
    {  // B tile: pre-split, pure copy
      const int r = tid >> 3, c4 = tid & 7;
#pragma unroll
      for (int rep = 0; rep < 4; ++rep) {
        const int row = r + rep * 32;
        const size_t off = (size_t)(col0 + row) * K + k0 + c4 * 4;
        *(u16x4*)&Bh[row * LK + c4 * 4] = *(const u16x4*)&Bhg[off];
        *(u16x4*)&Bl[row * LK + c4 * 4] = *(const u16x4*)&Blg[off];
      }
    }
    __syncthreads();

    s16x8 ah[4], al[4], bh[4], bl[4];
#pragma unroll
    for (int i = 0; i < 4; ++i) {
      ah[i] = *(const s16x8*)&Ah[(m0 + i*16 + mr) * LK + half * 8];
      al[i] = *(const s16x8*)&Al[(m0 + i*16 + mr) * LK + half * 8];
      bh[i] = *(const s16x8*)&Bh[(n0 + i*16 + mr) * LK + half * 8];
      bl[i] = *(const s16x8*)&Bl[(n0 + i*16 + mr) * LK + half * 8];
    }
#pragma unroll
    for (int i = 0; i < 4; ++i)
#pragma unroll
      for (int j = 0; j < 4; ++j) {
        acc[i][j] = __builtin_amdgcn_mfma_f32_16x16x32_bf16(ah[i], bh[j], acc[i][j], 0, 0, 0);
        acc[i][j] = __builtin_amdgcn_mfma_f32_16x16x32_bf16(ah[i], bl[j], acc[i][j], 0, 0, 0);
        acc[i][j] = __builtin_amdgcn_mfma_f32_16x16x32_bf16(al[i], bh[j], acc[i][j], 0, 0, 0);
      }
  }

#pragma unroll
  for (int j = 0; j < 4; ++j) {
    const int col = col0 + n0 + j * 16 + mr;
    const float bb = bias ? bias[col] : 0.f;
#pragma unroll
    for (int i = 0; i < 4; ++i) {
#pragma unroll
      for (int q = 0; q < 4; ++q) {
        const int row = row0 + m0 + i * 16 + half * 4 + q;
        C[(size_t)row * N + col] = fmaf(alpha, acc[i][j][q], bb);
      }
    }
  }
}

// =====================================================================
// tanh without an OCML call (abs err ~1e-7)
// =====================================================================
__device__ __forceinline__ float fast_tanh(float x) {
  const float a = fabsf(x);
  const float e = __expf(2.0f * a);
  const float t = 1.0f - 2.0f / (e + 1.0f);
  return copysignf(t, x);
}

// =====================================================================
// RNN scan v9 (r11/r12 EXACT — best validated 3.83 ms/scan; the r13
// handshake/pure-sc0 experiment is closed: unbounded sc0-only spin has
// no progress guarantee). Dual-visibility data-as-flag; wave0 poll +
// LDS broadcast; h-independent work hoisted ahead of the barrier.
// Scan BIT-IDENTICAL (canary: absmax exactly 0.0009765625).
// =====================================================================
__global__ __launch_bounds__(512, 1)
void rnn_scan(const float* __restrict__ Pre, float* __restrict__ Hout,
              const float* __restrict__ Whh, const float* __restrict__ bhh)
{
  __shared__ float wS[32][DIM];                 // 128 KB
  __shared__ __align__(16) float hbuf[2][DIM];  // 8 KB
  __shared__ float pS[8][8];
  const int b    = blockIdx.x & 7;
  const int p    = blockIdx.x >> 3;      // 0..31
  const int wv   = threadIdx.x >> 6;     // 0..7
  const int lane = threadIdx.x & 63;
  const int fl   = ((lane & 1) << 1) | ((lane >> 1) & 1);  // bitrev2

  const float* PreB = Pre  + (size_t)b * SEQ * DIM;
  float*       HB   = Hout + (size_t)b * SEQ * DIM;

  for (int i = threadIdx.x; i < 32 * (DIM / 4); i += 512) {
    const int row = i >> 8, c4 = i & 255;
    *(f32x4*)&wS[row][c4 * 4] =
        *(const f32x4*)&Whh[(size_t)(p * 32 + row) * DIM + c4 * 4];
  }
  __syncthreads();

  const bool w0lane = (wv == 0) && (lane < 32);
  const float biasv = w0lane ? bhh[p * 32 + lane] : 0.f;

  for (int t = 0; t < SEQ; ++t) {
    float pre = 0.f;
    if (w0lane) pre = PreB[(size_t)t * DIM + p * 32 + lane];

    f32x4 wr[4][4];
    if (wv != 0) {
#pragma unroll
      for (int r = 0; r < 4; ++r) {
        wr[r][0] = *(const f32x4*)&wS[wv * 4 + r][  0 + lane * 4];
        wr[r][1] = *(const f32x4*)&wS[wv * 4 + r][256 + lane * 4];
        wr[r][2] = *(const f32x4*)&wS[wv * 4 + r][512 + lane * 4];
        wr[r][3] = *(const f32x4*)&wS[wv * 4 + r][768 + lane * 4];
      }
    }

    if (t > 0) {
      if (wv == 0) {
        const float* hp = HB + (size_t)(t - 1) * DIM;
        const float* q0 = hp +   0 + lane * 4;
        const float* q1 = hp + 256 + lane * 4;
        const float* q2 = hp + 512 + lane * 4;
        const float* q3 = hp + 768 + lane * 4;
        f32x4 m0, m1, m2, m3;
        while (true) {
          f32x4 f0, f1, f2, f3;
          asm volatile(                      // FAST: own-XCD L2 view
            "global_load_dwordx4 %0, %4, off sc0\n\t"
            "global_load_dwordx4 %1, %5, off sc0\n\t"
            "global_load_dwordx4 %2, %6, off sc0\n\t"
            "global_load_dwordx4 %3, %7, off sc0\n\t"
            "s_waitcnt vmcnt(0)"
            : "=&v"(f0), "=&v"(f1), "=&v"(f2), "=&v"(f3)
            : "v"(q0), "v"(q1), "v"(q2), "v"(q3));
          bool gf = true;
#pragma unroll
          for (int j = 0; j < 4; ++j) {
            gf = gf && (__float_as_uint(f0[j]) != 0xFFFFFFFFu)
                    && (__float_as_uint(f1[j]) != 0xFFFFFFFFu)
                    && (__float_as_uint(f2[j]) != 0xFFFFFFFFu)
                    && (__float_as_uint(f3[j]) != 0xFFFFFFFFu);
          }
          if (__all(gf)) { m0 = f0; m1 = f1; m2 = f2; m3 = f3; break; }

          f32x4 s0, s1, s2, s3;
          asm volatile(                      // SLOW: L3 view (always correct)
            "global_load_dwordx4 %0, %4, off sc0 sc1\n\t"
            "global_load_dwordx4 %1, %5, off sc0 sc1\n\t"
            "global_load_dwordx4 %2, %6, off sc0 sc1\n\t"
            "global_load_dwordx4 %3, %7, off sc0 sc1\n\t"
            "s_waitcnt vmcnt(0)"
            : "=&v"(s0), "=&v"(s1), "=&v"(s2), "=&v"(s3)
            : "v"(q0), "v"(q1), "v"(q2), "v"(q3));
          bool gm = true;
#pragma unroll
          for (int j = 0; j < 4; ++j) {
            m0[j] = (__float_as_uint(f0[j]) != 0xFFFFFFFFu) ? f0[j] : s0[j];
            m1[j] = (__float_as_uint(f1[j]) != 0xFFFFFFFFu) ? f1[j] : s1[j];
            m2[j] = (__float_as_uint(f2[j]) != 0xFFFFFFFFu) ? f2[j] : s2[j];
            m3[j] = (__float_as_uint(f3[j]) != 0xFFFFFFFFu) ? f3[j] : s3[j];
            gm = gm && (__float_as_uint(m0[j]) != 0xFFFFFFFFu)
                    && (__float_as_uint(m1[j]) != 0xFFFFFFFFu)
                    && (__float_as_uint(m2[j]) != 0xFFFFFFFFu)
                    && (__float_as_uint(m3[j]) != 0xFFFFFFFFu);
          }
          if (__all(gm)) break;
        }
        *(f32x4*)&hbuf[t & 1][  0 + lane * 4] = m0;
        *(f32x4*)&hbuf[t & 1][256 + lane * 4] = m1;
        *(f32x4*)&hbuf[t & 1][512 + lane * 4] = m2;
        *(f32x4*)&hbuf[t & 1][768 + lane * 4] = m3;
#pragma unroll
        for (int r = 0; r < 4; ++r) {
          wr[r][0] = *(const f32x4*)&wS[wv * 4 + r][  0 + lane * 4];
          wr[r][1] = *(const f32x4*)&wS[wv * 4 + r][256 + lane * 4];
          wr[r][2] = *(const f32x4*)&wS[wv * 4 + r][512 + lane * 4];
          wr[r][3] = *(const f32x4*)&wS[wv * 4 + r][768 + lane * 4];
        }
      }
      __syncthreads();   // A: hbuf ready
      const f32x4 h0 = *(const f32x4*)&hbuf[t & 1][  0 + lane * 4];
      const f32x4 h1 = *(const f32x4*)&hbuf[t & 1][256 + lane * 4];
      const f32x4 h2 = *(const f32x4*)&hbuf[t & 1][512 + lane * 4];
      const f32x4 h3 = *(const f32x4*)&hbuf[t & 1][768 + lane * 4];
      float acc[4];
#pragma unroll
      for (int r = 0; r < 4; ++r) {
        float a = 0.f;
        a = fmaf(wr[r][0].x, h0.x, fmaf(wr[r][0].y, h0.y,
            fmaf(wr[r][0].z, h0.z, fmaf(wr[r][0].w, h0.w, a))));
        a = fmaf(wr[r][1].x, h1.x, fmaf(wr[r][1].y, h1.y,
            fmaf(wr[r][1].z, h1.z, fmaf(wr[r][1].w, h1.w, a))));
        a = fmaf(wr[r][2].x, h2.x, fmaf(wr[r][2].y, h2.y,
            fmaf(wr[r][2].z, h2.z, fmaf(wr[r][2].w, h2.w, a))));
        a = fmaf(wr[r][3].x, h3.x, fmaf(wr[r][3].y, h3.y,
            fmaf(wr[r][3].z, h3.z, fmaf(wr[r][3].w, h3.w, a))));
        acc[r] = a;
      }
#pragma unroll
      for (int m = 0; m < 2; ++m) {
        const int mask = 1 << m;
        const int nv   = 2 >> m;
        const bool up  = (lane & mask) != 0;
#pragma unroll
        for (int r = 0; r < nv; ++r) {
          const float lo = up ? acc[r + nv] : acc[r];
          const float hi = up ? acc[r] : acc[r + nv];
          acc[r] = lo + __shfl_xor(hi, mask);
        }
      }
#pragma unroll
      for (int off = 4; off < 64; off <<= 1) acc[0] += __shfl_xor(acc[0], off);

      if (lane < 4) pS[wv][fl] = acc[0];
      __syncthreads();   // B: pS ready
    }

    if (w0lane) {
      float s = (t > 0) ? (pre + pS[lane >> 2][lane & 3] + biasv)
                        : (pre + biasv);
      const float v = fast_tanh(s);
      float* dst = HB + (size_t)t * DIM + p * 32 + lane;
      asm volatile(
        "global_store_dword %0, %1, off sc0\n\t"
        "global_store_dword %0, %1, off sc0 sc1"
        :: "v"(dst), "v"(v));
    }
  }
}

// =====================================================================
// Masked softmax, in place, one row per block
// =====================================================================
__global__ __launch_bounds__(256)
void softmax_mask(float* __restrict__ S, const unsigned char* __restrict__ mask)
{
  const size_t row = (size_t)blockIdx.y * gridDim.x + blockIdx.x;
  float* p = S + row * SEQ;
  const unsigned char* mrow = mask + row * SEQ;
  __shared__ float buf[SEQ];
  __shared__ float red[4];
  const int tid = threadIdx.x, lane = tid & 63, wv = tid >> 6;

  float mx = -1e30f;
  for (int i = tid; i < SEQ; i += 256) {
    const float v = mrow[i] ? -1e9f : p[i];
    buf[i] = v;
    mx = fmaxf(mx, v);
  }
#pragma unroll
  for (int off = 1; off < 64; off <<= 1) mx = fmaxf(mx, __shfl_xor(mx, off));
  if (lane == 0) red[wv] = mx;
  __syncthreads();
  mx = fmaxf(fmaxf(red[0], red[1]), fmaxf(red[2], red[3]));

  float s = 0.f;
  for (int i = tid; i < SEQ; i += 256) {
    const float e = __expf(buf[i] - mx);
    buf[i] = e;
    s += e;
  }
#pragma unroll
  for (int off = 1; off < 64; off <<= 1) s += __shfl_xor(s, off);
  __syncthreads();
  if (lane == 0) red[wv] = s;
  __syncthreads();
  s = red[0] + red[1] + red[2] + red[3];
  const float inv = 1.f / s;
  for (int i = tid; i < SEQ; i += 256) p[i] = buf[i] * inv;
}

// =====================================================================
extern "C" void kernel_launch(void* const* d_in, const int* in_sizes, int n_in,
                              void* d_out, int out_size, void* d_ws, size_t ws_size,
                              hipStream_t stream)
{
  (void)in_sizes; (void)n_in; (void)out_size;
  const unsigned char* mask = (const unsigned char*)d_in[0];
  const float* reps = (const float*)d_in[1];
  const float* Wih  = (const float*)d_in[2];
  const float* Whh  = (const float*)d_in[3];
  const float* bih  = (const float*)d_in[4];
  const float* bhh  = (const float*)d_in[5];
  const float* Wq   = (const float*)d_in[6];
  const float* bq   = (const float*)d_in[7];
  const float* Wk   = (const float*)d_in[8];
  const float* bk   = (const float*)d_in[9];
  const float* Wv   = (const float*)d_in[10];
  const float* bv   = (const float*)d_in[11];
  const float* Wo   = (const float*)d_in[12];
  const float* bo   = (const float*)d_in[13];
  float* out = (float*)d_out;

  char* ws = (char*)d_ws;
  float* Hb = (float*)(ws);
  float* Qb = (float*)(ws + ((size_t)64  << 20));
  float* Kb = (float*)(ws + ((size_t)128 << 20));
  float* Vb = (float*)(ws + ((size_t)192 << 20));
  float* Sb = (float*)(ws + ((size_t)256 << 20));
  const size_t needFull = ((size_t)256 << 20) + (size_t)BATCH * SEQ * SEQ * 4;
  const bool fullS = ws_size >= needFull;
  // pre-split weight planes (10 x 2 MB) past the S buffer, gated on ws room
  const size_t MM = (size_t)DIM * DIM;
  unsigned short* wsp = (unsigned short*)(ws + needFull);
  const bool presplit = fullS && (ws_size >= needFull + ((size_t)20 << 20));
  const size_t hBytes = (size_t)BATCH * SEQ * DIM * 4;

  const int M1 = BATCH * SEQ;
  const float scale = 0.03125f;
  const dim3 blk(256);
  const dim3 projGrid(M1/128, DIM/128, 1);
  const long long sSD = (long long)SEQ * DIM;
  const long long sSS = (long long)SEQ * SEQ;
  const int splitGrid = (int)(MM / (256 * 4));   // 1024

  const float* X = reps;
  for (int l = 0; l < NLAYER; ++l) {
    const size_t wof = (size_t)l * DIM * DIM;
    const size_t bof = (size_t)l * DIM;
    float* Y = (l == NLAYER - 1) ? out : Qb;

    hipMemsetAsync(Hb, 0xFF, hBytes, stream);
    if (presplit) {
      split_mat<<<splitGrid, blk, 0, stream>>>(Wih + wof, wsp + 0*MM, wsp + 1*MM);
      split_mat<<<splitGrid, blk, 0, stream>>>(Wq  + wof, wsp + 2*MM, wsp + 3*MM);
      split_mat<<<splitGrid, blk, 0, stream>>>(Wk  + wof, wsp + 4*MM, wsp + 5*MM);
      split_mat<<<splitGrid, blk, 0, stream>>>(Wv  + wof, wsp + 6*MM, wsp + 7*MM);
      split_mat<<<splitGrid, blk, 0, stream>>>(Wo  + wof, wsp + 8*MM, wsp + 9*MM);
    }

    // Pre = X @ Wih^T + bih
    if (presplit)
      gemm_bsplit<<<projGrid, blk, 0, stream>>>(
          X, wsp + 0*MM, wsp + 1*MM, bih + bof, Kb, M1, DIM, DIM, 1.f);
    else
      gemm_bf16x3<1><<<projGrid, blk, 0, stream>>>(
          X, Wih + wof, bih + bof, Kb, M1, DIM, DIM, 1.f, 0, 0, 0);

    rnn_scan<<<dim3(256), dim3(512), 0, stream>>>(Kb, Hb, Whh + wof, bhh + bof);

    // Q/K/V projections
    if (presplit) {
      gemm_bsplit<<<projGrid, blk, 0, stream>>>(
          Hb, wsp + 2*MM, wsp + 3*MM, bq + bof, Qb, M1, DIM, DIM, 1.f);
      gemm_bsplit<<<projGrid, blk, 0, stream>>>(
          Hb, wsp + 4*MM, wsp + 5*MM, bk + bof, Kb, M1, DIM, DIM, 1.f);
      gemm_bsplit<<<projGrid, blk, 0, stream>>>(
          Hb, wsp + 6*MM, wsp + 7*MM, bv + bof, Vb, M1, DIM, DIM, 1.f);
    } else {
      gemm_bf16x3<1><<<projGrid, blk, 0, stream>>>(
          Hb, Wq + wof, bq + bof, Qb, M1, DIM, DIM, 1.f, 0, 0, 0);
      gemm_bf16x3<1><<<projGrid, blk, 0, stream>>>(
          Hb, Wk + wof, bk + bof, Kb, M1, DIM, DIM, 1.f, 0, 0, 0);
      gemm_bf16x3<1><<<projGrid, blk, 0, stream>>>(
          Hb, Wv + wof, bv + bof, Vb, M1, DIM, DIM, 1.f, 0, 0, 0);
    }

    if (fullS) {
      gemm_bf16x3<1><<<dim3(SEQ/128, SEQ/128, BATCH), blk, 0, stream>>>(
          Qb, Kb, nullptr, Sb, SEQ, SEQ, DIM, scale, sSD, sSD, sSS);
      softmax_mask<<<dim3(SEQ, BATCH), blk, 0, stream>>>(Sb, mask);
      gemm_bf16x3<0><<<dim3(SEQ/128, DIM/128, BATCH), blk, 0, stream>>>(
          Sb, Vb, nullptr, Hb, SEQ, DIM, SEQ, 1.f, sSS, sSD, sSD);
    } else {
      for (int bb = 0; bb < BATCH; ++bb) {
        gemm_bf16x3<1><<<dim3(SEQ/128, SEQ/128, 1), blk, 0, stream>>>(
            Qb + (size_t)bb * sSD, Kb + (size_t)bb * sSD, nullptr, Sb,
            SEQ, SEQ, DIM, scale, 0, 0, 0);
        softmax_mask<<<dim3(SEQ, 1), blk, 0, stream>>>(Sb, mask + (size_t)bb * sSS);
        gemm_bf16x3<0><<<dim3(SEQ/128, DIM/128, 1), blk, 0, stream>>>(
            Sb, Vb + (size_t)bb * sSD, nullptr, Hb + (size_t)bb * sSD,
            SEQ, DIM, SEQ, 1.f, 0, 0, 0);
      }
    }

    // layer output
    if (presplit)
      gemm_bsplit<<<projGrid, blk, 0, stream>>>(
          Hb, wsp + 8*MM, wsp + 9*MM, bo + bof, Y, M1, DIM, DIM, 1.f);
    else
      gemm_bf16x3<1><<<projGrid, blk, 0, stream>>>(
          Hb, Wo + wof, bo + bof, Y, M1, DIM, DIM, 1.f, 0, 0, 0);
    X = Y;
  }
}

// Round 15
// 10123.043 us; speedup vs baseline: 2.6981x; 1.0577x over previous
//
#include <hip/hip_runtime.h>
#include <hip/hip_bf16.h>

#define BATCH 8
#define SEQ   2048
#define DIM   1024
#define NLAYER 2

typedef float  f32x4 __attribute__((ext_vector_type(4)));
typedef short  s16x8 __attribute__((ext_vector_type(8)));
typedef unsigned short u16x4 __attribute__((ext_vector_type(4)));

// =====================================================================
// cheap bf16 split (r12): hi = HW RNE cast, lo = truncated residual
// =====================================================================
__device__ __forceinline__ void split_bf16(float x, unsigned short& hi, unsigned short& lo) {
  const __hip_bfloat16 hb = __float2bfloat16(x);          // HW RNE
  hi = *reinterpret_cast<const unsigned short*>(&hb);
  const float hf = __bfloat162float(hb);
  lo = (unsigned short)(__float_as_uint(x - hf) >> 16);   // truncate residual
}

// =====================================================================
// one-shot weight splitter: W (f32) -> Wh, Wl planes
// =====================================================================
__global__ __launch_bounds__(256)
void split_mat(const float* __restrict__ W, unsigned short* __restrict__ Wh,
               unsigned short* __restrict__ Wl)
{
  const int i = (blockIdx.x * 256 + threadIdx.x) * 4;
  const float4 v = *(const float4*)&W[i];
  unsigned short h0,h1,h2,h3,l0,l1,l2,l3;
  split_bf16(v.x, h0, l0); split_bf16(v.y, h1, l1);
  split_bf16(v.z, h2, l2); split_bf16(v.w, h3, l3);
  *(u16x4*)&Wh[i] = (u16x4){h0, h1, h2, h3};
  *(u16x4*)&Wl[i] = (u16x4){l0, l1, l2, l3};
}

// =====================================================================
// V transpose + split: V [SEQ][DIM] f32 -> Th,Tl [DIM][SEQ] u16 planes
// =====================================================================
__global__ __launch_bounds__(256)
void vtrans(const float* __restrict__ V, unsigned short* __restrict__ Th,
            unsigned short* __restrict__ Tl)
{
  __shared__ float t[64][65];
  const int z = blockIdx.z;
  V  += (size_t)z * SEQ * DIM;
  Th += (size_t)z * (size_t)DIM * SEQ;
  Tl += (size_t)z * (size_t)DIM * SEQ;
  const int s0 = blockIdx.x * 64, d0 = blockIdx.y * 64;
  const int tid = threadIdx.x;
#pragma unroll
  for (int rep = 0; rep < 4; ++rep) {
    const int idx = rep * 256 + tid;
    const int r = idx >> 4, c = idx & 15;      // r: s-row, c: d-chunk
    const float4 v = *(const float4*)&V[(size_t)(s0 + r) * DIM + d0 + c * 4];
    t[c*4+0][r] = v.x; t[c*4+1][r] = v.y; t[c*4+2][r] = v.z; t[c*4+3][r] = v.w;
  }
  __syncthreads();
#pragma unroll
  for (int rep = 0; rep < 4; ++rep) {
    const int idx = rep * 256 + tid;
    const int r = idx >> 4, c = idx & 15;      // r: d-row, c: s-chunk
    unsigned short h[4], l[4];
#pragma unroll
    for (int j = 0; j < 4; ++j) split_bf16(t[r][c*4+j], h[j], l[j]);
    const size_t off = (size_t)(d0 + r) * SEQ + s0 + c * 4;
    *(u16x4*)&Th[off] = (u16x4){h[0], h[1], h[2], h[3]};
    *(u16x4*)&Tl[off] = (u16x4){l[0], l[1], l[2], l[3]};
  }
}

// =====================================================================
// bf16x3 MFMA GEMM, A fp32 on-the-fly split, B pre-split planes (N x K).
// WS=1: epilogue writes split u16 planes Ch/Cl instead of fp32 C.
// z-batched via element strides.
// =====================================================================
template<int WS>
__global__ __launch_bounds__(256)
void gemm_bsplit(const float* __restrict__ A,
                 const unsigned short* __restrict__ Bhg,
                 const unsigned short* __restrict__ Blg,
                 const float* __restrict__ bias, float* __restrict__ C,
                 unsigned short* __restrict__ Ch, unsigned short* __restrict__ Cl,
                 int M, int N, int K, float alpha,
                 long long sA, long long sB, long long sC)
{
  constexpr int LK = 40;
  __shared__ unsigned short Ah[128 * LK], Al[128 * LK];
  __shared__ unsigned short Bh[128 * LK], Bl[128 * LK];

  const int z = blockIdx.z;
  A += (size_t)z * sA;
  Bhg += (size_t)z * sB;  Blg += (size_t)z * sB;
  if (WS) { Ch += (size_t)z * sC; Cl += (size_t)z * sC; }
  else    { C  += (size_t)z * sC; }

  const int tid  = threadIdx.x;
  const int row0 = blockIdx.x * 128;
  const int col0 = blockIdx.y * 128;
  const int w    = tid >> 6;
  const int lane = tid & 63;
  const int m0   = (w >> 1) * 64;
  const int n0   = (w & 1) * 64;
  const int half = lane >> 4;
  const int mr   = lane & 15;

  f32x4 acc[4][4];
#pragma unroll
  for (int i = 0; i < 4; ++i)
#pragma unroll
    for (int j = 0; j < 4; ++j) acc[i][j] = (f32x4){0.f, 0.f, 0.f, 0.f};

  for (int k0 = 0; k0 < K; k0 += 32) {
    __syncthreads();
    {  // A tile: split on the fly
      const int r = tid >> 3, c4 = tid & 7;
#pragma unroll
      for (int rep = 0; rep < 4; ++rep) {
        const int row = r + rep * 32;
        const float4 v = *(const float4*)&A[(size_t)(row0 + row) * K + k0 + c4 * 4];
        unsigned short h0,h1,h2,h3,l0,l1,l2,l3;
        split_bf16(v.x, h0, l0); split_bf16(v.y, h1, l1);
        split_bf16(v.z, h2, l2); split_bf16(v.w, h3, l3);
        *(u16x4*)&Ah[row * LK + c4 * 4] = (u16x4){h0, h1, h2, h3};
        *(u16x4*)&Al[row * LK + c4 * 4] = (u16x4){l0, l1, l2, l3};
      }
    }
    {  // B tile: pure copy
      const int r = tid >> 3, c4 = tid & 7;
#pragma unroll
      for (int rep = 0; rep < 4; ++rep) {
        const int row = r + rep * 32;
        const size_t off = (size_t)(col0 + row) * K + k0 + c4 * 4;
        *(u16x4*)&Bh[row * LK + c4 * 4] = *(const u16x4*)&Bhg[off];
        *(u16x4*)&Bl[row * LK + c4 * 4] = *(const u16x4*)&Blg[off];
      }
    }
    __syncthreads();

    s16x8 ah[4], al[4], bh[4], bl[4];
#pragma unroll
    for (int i = 0; i < 4; ++i) {
      ah[i] = *(const s16x8*)&Ah[(m0 + i*16 + mr) * LK + half * 8];
      al[i] = *(const s16x8*)&Al[(m0 + i*16 + mr) * LK + half * 8];
      bh[i] = *(const s16x8*)&Bh[(n0 + i*16 + mr) * LK + half * 8];
      bl[i] = *(const s16x8*)&Bl[(n0 + i*16 + mr) * LK + half * 8];
    }
#pragma unroll
    for (int i = 0; i < 4; ++i)
#pragma unroll
      for (int j = 0; j < 4; ++j) {
        acc[i][j] = __builtin_amdgcn_mfma_f32_16x16x32_bf16(ah[i], bh[j], acc[i][j], 0, 0, 0);
        acc[i][j] = __builtin_amdgcn_mfma_f32_16x16x32_bf16(ah[i], bl[j], acc[i][j], 0, 0, 0);
        acc[i][j] = __builtin_amdgcn_mfma_f32_16x16x32_bf16(al[i], bh[j], acc[i][j], 0, 0, 0);
      }
  }

#pragma unroll
  for (int j = 0; j < 4; ++j) {
    const int col = col0 + n0 + j * 16 + mr;
    const float bb = bias ? bias[col] : 0.f;
#pragma unroll
    for (int i = 0; i < 4; ++i) {
#pragma unroll
      for (int q = 0; q < 4; ++q) {
        const int row = row0 + m0 + i * 16 + half * 4 + q;
        const float val = fmaf(alpha, acc[i][j][q], bb);
        if (WS) {
          unsigned short h, l;
          split_bf16(val, h, l);
          Ch[(size_t)row * N + col] = h;
          Cl[(size_t)row * N + col] = l;
        } else {
          C[(size_t)row * N + col] = val;
        }
      }
    }
  }
}

// =====================================================================
// bf16x3 MFMA GEMM, BOTH operands pre-split (A: M x K, B: N x K planes).
// Zero split VALU. Used for QK^T. z-batched.
// =====================================================================
__global__ __launch_bounds__(256)
void gemm_absplit(const unsigned short* __restrict__ Ahg,
                  const unsigned short* __restrict__ Alg,
                  const unsigned short* __restrict__ Bhg,
                  const unsigned short* __restrict__ Blg,
                  float* __restrict__ C,
                  int M, int N, int K, float alpha,
                  long long sA, long long sB, long long sC)
{
  constexpr int LK = 40;
  __shared__ unsigned short Ah[128 * LK], Al[128 * LK];
  __shared__ unsigned short Bh[128 * LK], Bl[128 * LK];

  const int z = blockIdx.z;
  Ahg += (size_t)z * sA;  Alg += (size_t)z * sA;
  Bhg += (size_t)z * sB;  Blg += (size_t)z * sB;
  C   += (size_t)z * sC;

  const int tid  = threadIdx.x;
  const int row0 = blockIdx.x * 128;
  const int col0 = blockIdx.y * 128;
  const int w    = tid >> 6;
  const int lane = tid & 63;
  const int m0   = (w >> 1) * 64;
  const int n0   = (w & 1) * 64;
  const int half = lane >> 4;
  const int mr   = lane & 15;

  f32x4 acc[4][4];
#pragma unroll
  for (int i = 0; i < 4; ++i)
#pragma unroll
    for (int j = 0; j < 4; ++j) acc[i][j] = (f32x4){0.f, 0.f, 0.f, 0.f};

  for (int k0 = 0; k0 < K; k0 += 32) {
    __syncthreads();
    {
      const int r = tid >> 3, c4 = tid & 7;
#pragma unroll
      for (int rep = 0; rep < 4; ++rep) {
        const int row = r + rep * 32;
        const size_t offA = (size_t)(row0 + row) * K + k0 + c4 * 4;
        *(u16x4*)&Ah[row * LK + c4 * 4] = *(const u16x4*)&Ahg[offA];
        *(u16x4*)&Al[row * LK + c4 * 4] = *(const u16x4*)&Alg[offA];
        const size_t offB = (size_t)(col0 + row) * K + k0 + c4 * 4;
        *(u16x4*)&Bh[row * LK + c4 * 4] = *(const u16x4*)&Bhg[offB];
        *(u16x4*)&Bl[row * LK + c4 * 4] = *(const u16x4*)&Blg[offB];
      }
    }
    __syncthreads();

    s16x8 ah[4], al[4], bh[4], bl[4];
#pragma unroll
    for (int i = 0; i < 4; ++i) {
      ah[i] = *(const s16x8*)&Ah[(m0 + i*16 + mr) * LK + half * 8];
      al[i] = *(const s16x8*)&Al[(m0 + i*16 + mr) * LK + half * 8];
      bh[i] = *(const s16x8*)&Bh[(n0 + i*16 + mr) * LK + half * 8];
      bl[i] = *(const s16x8*)&Bl[(n0 + i*16 + mr) * LK + half * 8];
    }
#pragma unroll
    for (int i = 0; i < 4; ++i)
#pragma unroll
      for (int j = 0; j < 4; ++j) {
        acc[i][j] = __builtin_amdgcn_mfma_f32_16x16x32_bf16(ah[i], bh[j], acc[i][j], 0, 0, 0);
        acc[i][j] = __builtin_amdgcn_mfma_f32_16x16x32_bf16(ah[i], bl[j], acc[i][j], 0, 0, 0);
        acc[i][j] = __builtin_amdgcn_mfma_f32_16x16x32_bf16(al[i], bh[j], acc[i][j], 0, 0, 0);
      }
  }

#pragma unroll
  for (int j = 0; j < 4; ++j) {
    const int col = col0 + n0 + j * 16 + mr;
#pragma unroll
    for (int i = 0; i < 4; ++i) {
#pragma unroll
      for (int q = 0; q < 4; ++q) {
        const int row = row0 + m0 + i * 16 + half * 4 + q;
        C[(size_t)row * N + col] = alpha * acc[i][j][q];
      }
    }
  }
}

// =====================================================================
// r12 on-the-fly GEMM (fallback path when ws too small)
// =====================================================================
template<int TRANSB>
__global__ __launch_bounds__(256)
void gemm_bf16x3(const float* __restrict__ A, const float* __restrict__ B,
                 const float* __restrict__ bias, float* __restrict__ C,
                 int M, int N, int K, float alpha,
                 long long strideA, long long strideB, long long strideC)
{
  constexpr int LK = 40;
  __shared__ unsigned short Ah[128 * LK], Al[128 * LK];
  __shared__ unsigned short Bh[128 * LK], Bl[128 * LK];

  const int z = blockIdx.z;
  A += (size_t)z * strideA;
  B += (size_t)z * strideB;
  C += (size_t)z * strideC;

  const int tid  = threadIdx.x;
  const int row0 = blockIdx.x * 128;
  const int col0 = blockIdx.y * 128;
  const int w    = tid >> 6;
  const int lane = tid & 63;
  const int m0   = (w >> 1) * 64;
  const int n0   = (w & 1) * 64;
  const int half = lane >> 4;
  const int mr   = lane & 15;

  f32x4 acc[4][4];
#pragma unroll
  for (int i = 0; i < 4; ++i)
#pragma unroll
    for (int j = 0; j < 4; ++j) acc[i][j] = (f32x4){0.f, 0.f, 0.f, 0.f};

  for (int k0 = 0; k0 < K; k0 += 32) {
    __syncthreads();
    {
      const int r = tid >> 3, c4 = tid & 7;
#pragma unroll
      for (int rep = 0; rep < 4; ++rep) {
        const int row = r + rep * 32;
        const float4 v = *(const float4*)&A[(size_t)(row0 + row) * K + k0 + c4 * 4];
        unsigned short h0,h1,h2,h3,l0,l1,l2,l3;
        split_bf16(v.x, h0, l0); split_bf16(v.y, h1, l1);
        split_bf16(v.z, h2, l2); split_bf16(v.w, h3, l3);
        *(u16x4*)&Ah[row * LK + c4 * 4] = (u16x4){h0, h1, h2, h3};
        *(u16x4*)&Al[row * LK + c4 * 4] = (u16x4){l0, l1, l2, l3};
      }
    }
    if (TRANSB) {
      const int r = tid >> 3, c4 = tid & 7;
#pragma unroll
      for (int rep = 0; rep < 4; ++rep) {
        const int row = r + rep * 32;
        const float4 v = *(const float4*)&B[(size_t)(col0 + row) * K + k0 + c4 * 4];
        unsigned short h0,h1,h2,h3,l0,l1,l2,l3;
        split_bf16(v.x, h0, l0); split_bf16(v.y, h1, l1);
        split_bf16(v.z, h2, l2); split_bf16(v.w, h3, l3);
        *(u16x4*)&Bh[row * LK + c4 * 4] = (u16x4){h0, h1, h2, h3};
        *(u16x4*)&Bl[row * LK + c4 * 4] = (u16x4){l0, l1, l2, l3};
      }
    } else {
      const int kk8 = tid >> 5, n4 = tid & 31;
#pragma unroll
      for (int rep = 0; rep < 4; ++rep) {
        const int kk = kk8 + rep * 8;
        const float4 v = *(const float4*)&B[(size_t)(k0 + kk) * N + col0 + n4 * 4];
        unsigned short h, l;
        split_bf16(v.x, h, l); Bh[(n4*4+0)*LK + kk] = h; Bl[(n4*4+0)*LK + kk] = l;
        split_bf16(v.y, h, l); Bh[(n4*4+1)*LK + kk] = h; Bl[(n4*4+1)*LK + kk] = l;
        split_bf16(v.z, h, l); Bh[(n4*4+2)*LK + kk] = h; Bl[(n4*4+2)*LK + kk] = l;
        split_bf16(v.w, h, l); Bh[(n4*4+3)*LK + kk] = h; Bl[(n4*4+3)*LK + kk] = l;
      }
    }
    __syncthreads();

    s16x8 ah[4], al[4], bh[4], bl[4];
#pragma unroll
    for (int i = 0; i < 4; ++i) {
      ah[i] = *(const s16x8*)&Ah[(m0 + i*16 + mr) * LK + half * 8];
      al[i] = *(const s16x8*)&Al[(m0 + i*16 + mr) * LK + half * 8];
      bh[i] = *(const s16x8*)&Bh[(n0 + i*16 + mr) * LK + half * 8];
      bl[i] = *(const s16x8*)&Bl[(n0 + i*16 + mr) * LK + half * 8];
    }
#pragma unroll
    for (int i = 0; i < 4; ++i)
#pragma unroll
      for (int j = 0; j < 4; ++j) {
        acc[i][j] = __builtin_amdgcn_mfma_f32_16x16x32_bf16(ah[i], bh[j], acc[i][j], 0, 0, 0);
        acc[i][j] = __builtin_amdgcn_mfma_f32_16x16x32_bf16(ah[i], bl[j], acc[i][j], 0, 0, 0);
        acc[i][j] = __builtin_amdgcn_mfma_f32_16x16x32_bf16(al[i], bh[j], acc[i][j], 0, 0, 0);
      }
  }

#pragma unroll
  for (int j = 0; j < 4; ++j) {
    const int col = col0 + n0 + j * 16 + mr;
    const float bb = bias ? bias[col] : 0.f;
#pragma unroll
    for (int i = 0; i < 4; ++i) {
#pragma unroll
      for (int q = 0; q < 4; ++q) {
        const int row = row0 + m0 + i * 16 + half * 4 + q;
        C[(size_t)row * N + col] = fmaf(alpha, acc[i][j][q], bb);
      }
    }
  }
}

// =====================================================================
// tanh without an OCML call (abs err ~1e-7)
// =====================================================================
__device__ __forceinline__ float fast_tanh(float x) {
  const float a = fabsf(x);
  const float e = __expf(2.0f * a);
  const float t = 1.0f - 2.0f / (e + 1.0f);
  return copysignf(t, x);
}

// =====================================================================
// RNN scan v9 (r11/r12 EXACT — best validated 3.83 ms/scan).
// Scan BIT-IDENTICAL (canary: absmax exactly 0.0009765625).
// =====================================================================
__global__ __launch_bounds__(512, 1)
void rnn_scan(const float* __restrict__ Pre, float* __restrict__ Hout,
              const float* __restrict__ Whh, const float* __restrict__ bhh)
{
  __shared__ float wS[32][DIM];                 // 128 KB
  __shared__ __align__(16) float hbuf[2][DIM];  // 8 KB
  __shared__ float pS[8][8];
  const int b    = blockIdx.x & 7;
  const int p    = blockIdx.x >> 3;      // 0..31
  const int wv   = threadIdx.x >> 6;     // 0..7
  const int lane = threadIdx.x & 63;
  const int fl   = ((lane & 1) << 1) | ((lane >> 1) & 1);  // bitrev2

  const float* PreB = Pre  + (size_t)b * SEQ * DIM;
  float*       HB   = Hout + (size_t)b * SEQ * DIM;

  for (int i = threadIdx.x; i < 32 * (DIM / 4); i += 512) {
    const int row = i >> 8, c4 = i & 255;
    *(f32x4*)&wS[row][c4 * 4] =
        *(const f32x4*)&Whh[(size_t)(p * 32 + row) * DIM + c4 * 4];
  }
  __syncthreads();

  const bool w0lane = (wv == 0) && (lane < 32);
  const float biasv = w0lane ? bhh[p * 32 + lane] : 0.f;

  for (int t = 0; t < SEQ; ++t) {
    float pre = 0.f;
    if (w0lane) pre = PreB[(size_t)t * DIM + p * 32 + lane];

    f32x4 wr[4][4];
    if (wv != 0) {
#pragma unroll
      for (int r = 0; r < 4; ++r) {
        wr[r][0] = *(const f32x4*)&wS[wv * 4 + r][  0 + lane * 4];
        wr[r][1] = *(const f32x4*)&wS[wv * 4 + r][256 + lane * 4];
        wr[r][2] = *(const f32x4*)&wS[wv * 4 + r][512 + lane * 4];
        wr[r][3] = *(const f32x4*)&wS[wv * 4 + r][768 + lane * 4];
      }
    }

    if (t > 0) {
      if (wv == 0) {
        const float* hp = HB + (size_t)(t - 1) * DIM;
        const float* q0 = hp +   0 + lane * 4;
        const float* q1 = hp + 256 + lane * 4;
        const float* q2 = hp + 512 + lane * 4;
        const float* q3 = hp + 768 + lane * 4;
        f32x4 m0, m1, m2, m3;
        while (true) {
          f32x4 f0, f1, f2, f3;
          asm volatile(                      // FAST: own-XCD L2 view
            "global_load_dwordx4 %0, %4, off sc0\n\t"
            "global_load_dwordx4 %1, %5, off sc0\n\t"
            "global_load_dwordx4 %2, %6, off sc0\n\t"
            "global_load_dwordx4 %3, %7, off sc0\n\t"
            "s_waitcnt vmcnt(0)"
            : "=&v"(f0), "=&v"(f1), "=&v"(f2), "=&v"(f3)
            : "v"(q0), "v"(q1), "v"(q2), "v"(q3));
          bool gf = true;
#pragma unroll
          for (int j = 0; j < 4; ++j) {
            gf = gf && (__float_as_uint(f0[j]) != 0xFFFFFFFFu)
                    && (__float_as_uint(f1[j]) != 0xFFFFFFFFu)
                    && (__float_as_uint(f2[j]) != 0xFFFFFFFFu)
                    && (__float_as_uint(f3[j]) != 0xFFFFFFFFu);
          }
          if (__all(gf)) { m0 = f0; m1 = f1; m2 = f2; m3 = f3; break; }

          f32x4 s0, s1, s2, s3;
          asm volatile(                      // SLOW: L3 view (always correct)
            "global_load_dwordx4 %0, %4, off sc0 sc1\n\t"
            "global_load_dwordx4 %1, %5, off sc0 sc1\n\t"
            "global_load_dwordx4 %2, %6, off sc0 sc1\n\t"
            "global_load_dwordx4 %3, %7, off sc0 sc1\n\t"
            "s_waitcnt vmcnt(0)"
            : "=&v"(s0), "=&v"(s1), "=&v"(s2), "=&v"(s3)
            : "v"(q0), "v"(q1), "v"(q2), "v"(q3));
          bool gm = true;
#pragma unroll
          for (int j = 0; j < 4; ++j) {
            m0[j] = (__float_as_uint(f0[j]) != 0xFFFFFFFFu) ? f0[j] : s0[j];
            m1[j] = (__float_as_uint(f1[j]) != 0xFFFFFFFFu) ? f1[j] : s1[j];
            m2[j] = (__float_as_uint(f2[j]) != 0xFFFFFFFFu) ? f2[j] : s2[j];
            m3[j] = (__float_as_uint(f3[j]) != 0xFFFFFFFFu) ? f3[j] : s3[j];
            gm = gm && (__float_as_uint(m0[j]) != 0xFFFFFFFFu)
                    && (__float_as_uint(m1[j]) != 0xFFFFFFFFu)
                    && (__float_as_uint(m2[j]) != 0xFFFFFFFFu)
                    && (__float_as_uint(m3[j]) != 0xFFFFFFFFu);
          }
          if (__all(gm)) break;
        }
        *(f32x4*)&hbuf[t & 1][  0 + lane * 4] = m0;
        *(f32x4*)&hbuf[t & 1][256 + lane * 4] = m1;
        *(f32x4*)&hbuf[t & 1][512 + lane * 4] = m2;
        *(f32x4*)&hbuf[t & 1][768 + lane * 4] = m3;
#pragma unroll
        for (int r = 0; r < 4; ++r) {
          wr[r][0] = *(const f32x4*)&wS[wv * 4 + r][  0 + lane * 4];
          wr[r][1] = *(const f32x4*)&wS[wv * 4 + r][256 + lane * 4];
          wr[r][2] = *(const f32x4*)&wS[wv * 4 + r][512 + lane * 4];
          wr[r][3] = *(const f32x4*)&wS[wv * 4 + r][768 + lane * 4];
        }
      }
      __syncthreads();   // A: hbuf ready
      const f32x4 h0 = *(const f32x4*)&hbuf[t & 1][  0 + lane * 4];
      const f32x4 h1 = *(const f32x4*)&hbuf[t & 1][256 + lane * 4];
      const f32x4 h2 = *(const f32x4*)&hbuf[t & 1][512 + lane * 4];
      const f32x4 h3 = *(const f32x4*)&hbuf[t & 1][768 + lane * 4];
      float acc[4];
#pragma unroll
      for (int r = 0; r < 4; ++r) {
        float a = 0.f;
        a = fmaf(wr[r][0].x, h0.x, fmaf(wr[r][0].y, h0.y,
            fmaf(wr[r][0].z, h0.z, fmaf(wr[r][0].w, h0.w, a))));
        a = fmaf(wr[r][1].x, h1.x, fmaf(wr[r][1].y, h1.y,
            fmaf(wr[r][1].z, h1.z, fmaf(wr[r][1].w, h1.w, a))));
        a = fmaf(wr[r][2].x, h2.x, fmaf(wr[r][2].y, h2.y,
            fmaf(wr[r][2].z, h2.z, fmaf(wr[r][2].w, h2.w, a))));
        a = fmaf(wr[r][3].x, h3.x, fmaf(wr[r][3].y, h3.y,
            fmaf(wr[r][3].z, h3.z, fmaf(wr[r][3].w, h3.w, a))));
        acc[r] = a;
      }
#pragma unroll
      for (int m = 0; m < 2; ++m) {
        const int mask = 1 << m;
        const int nv   = 2 >> m;
        const bool up  = (lane & mask) != 0;
#pragma unroll
        for (int r = 0; r < nv; ++r) {
          const float lo = up ? acc[r + nv] : acc[r];
          const float hi = up ? acc[r] : acc[r + nv];
          acc[r] = lo + __shfl_xor(hi, mask);
        }
      }
#pragma unroll
      for (int off = 4; off < 64; off <<= 1) acc[0] += __shfl_xor(acc[0], off);

      if (lane < 4) pS[wv][fl] = acc[0];
      __syncthreads();   // B: pS ready
    }

    if (w0lane) {
      float s = (t > 0) ? (pre + pS[lane >> 2][lane & 3] + biasv)
                        : (pre + biasv);
      const float v = fast_tanh(s);
      float* dst = HB + (size_t)t * DIM + p * 32 + lane;
      asm volatile(
        "global_store_dword %0, %1, off sc0\n\t"
        "global_store_dword %0, %1, off sc0 sc1"
        :: "v"(dst), "v"(v));
    }
  }
}

// =====================================================================
// Masked softmax, in place, one row per block
// =====================================================================
__global__ __launch_bounds__(256)
void softmax_mask(float* __restrict__ S, const unsigned char* __restrict__ mask)
{
  const size_t row = (size_t)blockIdx.y * gridDim.x + blockIdx.x;
  float* p = S + row * SEQ;
  const unsigned char* mrow = mask + row * SEQ;
  __shared__ float buf[SEQ];
  __shared__ float red[4];
  const int tid = threadIdx.x, lane = tid & 63, wv = tid >> 6;

  float mx = -1e30f;
  for (int i = tid; i < SEQ; i += 256) {
    const float v = mrow[i] ? -1e9f : p[i];
    buf[i] = v;
    mx = fmaxf(mx, v);
  }
#pragma unroll
  for (int off = 1; off < 64; off <<= 1) mx = fmaxf(mx, __shfl_xor(mx, off));
  if (lane == 0) red[wv] = mx;
  __syncthreads();
  mx = fmaxf(fmaxf(red[0], red[1]), fmaxf(red[2], red[3]));

  float s = 0.f;
  for (int i = tid; i < SEQ; i += 256) {
    const float e = __expf(buf[i] - mx);
    buf[i] = e;
    s += e;
  }
#pragma unroll
  for (int off = 1; off < 64; off <<= 1) s += __shfl_xor(s, off);
  __syncthreads();
  if (lane == 0) red[wv] = s;
  __syncthreads();
  s = red[0] + red[1] + red[2] + red[3];
  const float inv = 1.f / s;
  for (int i = tid; i < SEQ; i += 256) p[i] = buf[i] * inv;
}

// =====================================================================
extern "C" void kernel_launch(void* const* d_in, const int* in_sizes, int n_in,
                              void* d_out, int out_size, void* d_ws, size_t ws_size,
                              hipStream_t stream)
{
  (void)in_sizes; (void)n_in; (void)out_size;
  const unsigned char* mask = (const unsigned char*)d_in[0];
  const float* reps = (const float*)d_in[1];
  const float* Wih  = (const float*)d_in[2];
  const float* Whh  = (const float*)d_in[3];
  const float* bih  = (const float*)d_in[4];
  const float* bhh  = (const float*)d_in[5];
  const float* Wq   = (const float*)d_in[6];
  const float* bq   = (const float*)d_in[7];
  const float* Wk   = (const float*)d_in[8];
  const float* bk   = (const float*)d_in[9];
  const float* Wv   = (const float*)d_in[10];
  const float* bv   = (const float*)d_in[11];
  const float* Wo   = (const float*)d_in[12];
  const float* bo   = (const float*)d_in[13];
  float* out = (float*)d_out;

  char* ws = (char*)d_ws;
  float* Hb = (float*)(ws);
  float* Qb = (float*)(ws + ((size_t)64  << 20));
  float* Kb = (float*)(ws + ((size_t)128 << 20));
  float* Vb = (float*)(ws + ((size_t)192 << 20));
  float* Sb = (float*)(ws + ((size_t)256 << 20));
  const size_t needFull = ((size_t)256 << 20) + (size_t)BATCH * SEQ * SEQ * 4;
  const bool fullS = ws_size >= needFull;
  const size_t MM = (size_t)DIM * DIM;
  unsigned short* wsp = (unsigned short*)(ws + needFull);
  const bool presplit = fullS && (ws_size >= needFull + ((size_t)20 << 20));
  const size_t hBytes = (size_t)BATCH * SEQ * DIM * 4;

  const int M1 = BATCH * SEQ;
  const size_t PL = (size_t)M1 * DIM;     // one u16 plane, all batches
  const float scale = 0.03125f;
  const dim3 blk(256);
  const dim3 projGrid(M1/128, DIM/128, 1);
  const long long sSD = (long long)SEQ * DIM;
  const long long sSS = (long long)SEQ * SEQ;
  const int splitGrid = (int)(MM / (256 * 4));

  // u16 plane views inside existing buffers
  unsigned short* Qh = (unsigned short*)Qb;  unsigned short* Ql = Qh + PL;
  unsigned short* Kh = (unsigned short*)Kb;  unsigned short* Kl = Kh + PL;
  unsigned short* Vth = (unsigned short*)Vb; unsigned short* Vtl = Vth + PL;

  const float* X = reps;
  for (int l = 0; l < NLAYER; ++l) {
    const size_t wof = (size_t)l * DIM * DIM;
    const size_t bof = (size_t)l * DIM;
    float* Y = (l == NLAYER - 1) ? out : Qb;

    hipMemsetAsync(Hb, 0xFF, hBytes, stream);
    if (presplit) {
      split_mat<<<splitGrid, blk, 0, stream>>>(Wih + wof, wsp + 0*MM, wsp + 1*MM);
      split_mat<<<splitGrid, blk, 0, stream>>>(Wq  + wof, wsp + 2*MM, wsp + 3*MM);
      split_mat<<<splitGrid, blk, 0, stream>>>(Wk  + wof, wsp + 4*MM, wsp + 5*MM);
      split_mat<<<splitGrid, blk, 0, stream>>>(Wv  + wof, wsp + 6*MM, wsp + 7*MM);
      split_mat<<<splitGrid, blk, 0, stream>>>(Wo  + wof, wsp + 8*MM, wsp + 9*MM);

      // Pre = X @ Wih^T + bih -> Kb (fp32)
      gemm_bsplit<0><<<projGrid, blk, 0, stream>>>(
          X, wsp + 0*MM, wsp + 1*MM, bih + bof, Kb, nullptr, nullptr,
          M1, DIM, DIM, 1.f, 0, 0, 0);
      rnn_scan<<<dim3(256), dim3(512), 0, stream>>>(Kb, Hb, Whh + wof, bhh + bof);

      // Q, K projections -> pre-split planes (bit-identical values)
      gemm_bsplit<1><<<projGrid, blk, 0, stream>>>(
          Hb, wsp + 2*MM, wsp + 3*MM, bq + bof, nullptr, Qh, Ql,
          M1, DIM, DIM, 1.f, 0, 0, 0);
      gemm_bsplit<1><<<projGrid, blk, 0, stream>>>(
          Hb, wsp + 4*MM, wsp + 5*MM, bk + bof, nullptr, Kh, Kl,
          M1, DIM, DIM, 1.f, 0, 0, 0);
      // V projection -> fp32 scratch (Sb), then transpose+split -> Vt planes
      gemm_bsplit<0><<<projGrid, blk, 0, stream>>>(
          Hb, wsp + 6*MM, wsp + 7*MM, bv + bof, Sb, nullptr, nullptr,
          M1, DIM, DIM, 1.f, 0, 0, 0);
      vtrans<<<dim3(SEQ/64, DIM/64, BATCH), blk, 0, stream>>>(Sb, Vth, Vtl);

      // scores: both operands pre-split, pure-copy staging
      gemm_absplit<<<dim3(SEQ/128, SEQ/128, BATCH), blk, 0, stream>>>(
          Qh, Ql, Kh, Kl, Sb, SEQ, SEQ, DIM, scale, sSD, sSD, sSS);
      softmax_mask<<<dim3(SEQ, BATCH), blk, 0, stream>>>(Sb, mask);
      // PV: A = S fp32 (on-the-fly), B = V^T planes (copy)
      gemm_bsplit<0><<<dim3(SEQ/128, DIM/128, BATCH), blk, 0, stream>>>(
          Sb, Vth, Vtl, nullptr, Hb, nullptr, nullptr,
          SEQ, DIM, SEQ, 1.f, sSS, (long long)DIM * SEQ, sSD);
      // layer output
      gemm_bsplit<0><<<projGrid, blk, 0, stream>>>(
          Hb, wsp + 8*MM, wsp + 9*MM, bo + bof, Y, nullptr, nullptr,
          M1, DIM, DIM, 1.f, 0, 0, 0);
    } else {
      // fallback: r12 path
      gemm_bf16x3<1><<<projGrid, blk, 0, stream>>>(
          X, Wih + wof, bih + bof, Kb, M1, DIM, DIM, 1.f, 0, 0, 0);
      rnn_scan<<<dim3(256), dim3(512), 0, stream>>>(Kb, Hb, Whh + wof, bhh + bof);
      gemm_bf16x3<1><<<projGrid, blk, 0, stream>>>(
          Hb, Wq + wof, bq + bof, Qb, M1, DIM, DIM, 1.f, 0, 0, 0);
      gemm_bf16x3<1><<<projGrid, blk, 0, stream>>>(
          Hb, Wk + wof, bk + bof, Kb, M1, DIM, DIM, 1.f, 0, 0, 0);
      gemm_bf16x3<1><<<projGrid, blk, 0, stream>>>(
          Hb, Wv + wof, bv + bof, Vb, M1, DIM, DIM, 1.f, 0, 0, 0);
      if (fullS) {
        gemm_bf16x3<1><<<dim3(SEQ/128, SEQ/128, BATCH), blk, 0, stream>>>(
            Qb, Kb, nullptr, Sb, SEQ, SEQ, DIM, scale, sSD, sSD, sSS);
        softmax_mask<<<dim3(SEQ, BATCH), blk, 0, stream>>>(Sb, mask);
        gemm_bf16x3<0><<<dim3(SEQ/128, DIM/128, BATCH), blk, 0, stream>>>(
            Sb, Vb, nullptr, Hb, SEQ, DIM, SEQ, 1.f, sSS, sSD, sSD);
      } else {
        for (int bb = 0; bb < BATCH; ++bb) {
          gemm_bf16x3<1><<<dim3(SEQ/128, SEQ/128, 1), blk, 0, stream>>>(
              Qb + (size_t)bb * sSD, Kb + (size_t)bb * sSD, nullptr, Sb,
              SEQ, SEQ, DIM, scale, 0, 0, 0);
          softmax_mask<<<dim3(SEQ, 1), blk, 0, stream>>>(Sb, mask + (size_t)bb * sSS);
          gemm_bf16x3<0><<<dim3(SEQ/128, DIM/128, 1), blk, 0, stream>>>(
              Sb, Vb + (size_t)bb * sSD, nullptr, Hb + (size_t)bb * sSD,
              SEQ, DIM, SEQ, 1.f, 0, 0, 0);
        }
      }
      gemm_bf16x3<1><<<projGrid, blk, 0, stream>>>(
          Hb, Wo + wof, bo + bof, Y, M1, DIM, DIM, 1.f, 0, 0, 0);
    }
    X = Y;
  }
}